// Round 11
// baseline (436.986 us; speedup 1.0000x reference)
//
#include <hip/hip_runtime.h>
#include <hip/hip_fp16.h>

#define N_NODES 40000
#define N_EDGES 640000
#define DIM 128
#define N_GRAPHS 64
#define BN_EPS 1e-5f
#define AGG_BLOCKS 2048
#define SCAN_NB 40   // ceil(40000/1024)
#define GEMM_NB (N_NODES / 64)   // 625 blocks x 64 rows (exact)
#define WTP 136                  // padded k-stride for Wt / A tiles (halves)

typedef _Float16 f16x8 __attribute__((ext_vector_type(8)));
typedef float    f32x4 __attribute__((ext_vector_type(4)));

// ---------------- CSR build ----------------
__global__ __launch_bounds__(256) void k_count_edges(const int* __restrict__ ei, int* __restrict__ cnt) {
    int e = blockIdx.x * 256 + threadIdx.x;
    if (e < N_EDGES) atomicAdd(&cnt[ei[N_EDGES + e]], 1);   // dst row
}

// batch is sorted: graph offsets are boundaries (no atomics).
__global__ __launch_bounds__(256) void k_boundaries(const int* __restrict__ batch, int* __restrict__ goff) {
    int n = blockIdx.x * 256 + threadIdx.x;
    if (n >= N_NODES) return;
    int b = batch[n];
    int bp = (n == 0) ? -1 : batch[n - 1];
    for (int g = bp + 1; g <= b; ++g) goff[g] = n;          // rare divergence
    if (n == N_NODES - 1)
        for (int g = b + 1; g <= N_GRAPHS; ++g) goff[g] = N_NODES;
}

// ---- 3-pass parallel exclusive scan of cnt -> off, plus pos/dinv fill ----
__global__ __launch_bounds__(1024) void k_scan_blk(const int* __restrict__ cnt, int* __restrict__ off,
                                                   int* __restrict__ blocksum) {
    __shared__ int sums[1024];
    int i = blockIdx.x * 1024 + threadIdx.x;
    int v = (i < N_NODES) ? cnt[i] : 0;
    sums[threadIdx.x] = v;
    __syncthreads();
    for (int d = 1; d < 1024; d <<= 1) {
        int t = (threadIdx.x >= d) ? sums[threadIdx.x - d] : 0;
        __syncthreads();
        sums[threadIdx.x] += t;
        __syncthreads();
    }
    if (i < N_NODES) off[i] = sums[threadIdx.x] - v;        // exclusive within block
    if (threadIdx.x == 1023) blocksum[blockIdx.x] = sums[1023];
}

__global__ void k_scan_tops(const int* __restrict__ blocksum, int* __restrict__ blockoff) {
    if (threadIdx.x == 0) {
        int run = 0;
        for (int b = 0; b < SCAN_NB; ++b) { blockoff[b] = run; run += blocksum[b]; }
        blockoff[SCAN_NB] = run;
    }
}

__global__ __launch_bounds__(1024) void k_scan_fix(const int* __restrict__ cnt, const int* __restrict__ blockoff,
                                                   int* __restrict__ off, int* __restrict__ pos,
                                                   float* __restrict__ dinv) {
    int i = blockIdx.x * 1024 + threadIdx.x;
    if (i < N_NODES) {
        int o = off[i] + blockoff[blockIdx.x];
        off[i] = o; pos[i] = o;
        dinv[i] = rsqrtf((float)(cnt[i] + 1));              // +1 self loop, always > 0
    }
    if (i == 0) off[N_NODES] = blockoff[SCAN_NB];
}

// scatter src index only (4B): coef is recomputed in k_agg from dinv
__global__ __launch_bounds__(256) void k_fill(const int* __restrict__ ei, int* __restrict__ pos,
                                              int* __restrict__ elist) {
    int e = blockIdx.x * 256 + threadIdx.x;
    if (e < N_EDGES) {
        int s = ei[e];                 // src row
        int d = ei[N_EDGES + e];       // dst row
        int p = atomicAdd(&pos[d], 1);
        elist[p] = s;
    }
}

// ---- W prep: per layer, transposed hi/lo fp16 split, padded [c][WTP] ----
// wt layout: [layer][2][128][WTP] halves; W = hi + lo to ~2^-22 rel.
__global__ __launch_bounds__(256) void k_prepw(const float* __restrict__ Ws, __half* __restrict__ wt) {
    int idx = blockIdx.x * 256 + threadIdx.x;        // 3*128*128
    if (idx >= 3 * DIM * DIM) return;
    int l = idx >> 14;
    int rem = idx & 16383;
    int k = rem >> 7;         // row of W
    int c = rem & 127;        // col of W
    float w = Ws[(size_t)l * DIM * DIM + k * DIM + c];
    __half hi = __float2half(w);
    __half lo = __float2half(w - __half2float(hi));
    size_t base = (size_t)l * 2 * DIM * WTP;
    wt[base + (size_t)c * WTP + k] = hi;
    wt[base + (size_t)DIM * WTP + (size_t)c * WTP + k] = lo;
}

// ---------------- GEMM via MFMA: out16 = fp16( affine(in) @ W + b ) -------
__global__ __launch_bounds__(256) void k_gemm(const float* __restrict__ in, const __half* __restrict__ wt2,
                                              const float* __restrict__ bias, const float* __restrict__ ac,
                                              __half* __restrict__ out16) {
    __shared__ __half Wl2[2 * DIM * WTP];   // hi then lo
    __shared__ __half Al[64 * WTP];
    int t = threadIdx.x;
    long row0 = (long)blockIdx.x * 64;

    {   // stage Wt hi+lo: 2*128*136 halves = 4352 float4
        const float4* src = (const float4*)wt2;
        float4* dst = (float4*)Wl2;
        for (int i = t; i < 4352; i += 256) dst[i] = src[i];
    }
    for (int i = t; i < 2048; i += 256) {   // A: 64 rows x 32 float4
        int r = i >> 5, k4 = i & 31;
        float4 v = ((const float4*)(in + (row0 + r) * DIM))[k4];
        if (ac) {
            int k = k4 * 4;
            v.x = fmaf(ac[k + 0], v.x, ac[DIM + k + 0]);
            v.y = fmaf(ac[k + 1], v.y, ac[DIM + k + 1]);
            v.z = fmaf(ac[k + 2], v.z, ac[DIM + k + 2]);
            v.w = fmaf(ac[k + 3], v.w, ac[DIM + k + 3]);
        }
        __half2* d = (__half2*)&Al[r * WTP + k4 * 4];
        d[0] = __floats2half2_rn(v.x, v.y);
        d[1] = __floats2half2_rn(v.z, v.w);
    }
    __syncthreads();

    int w = t >> 6;            // wave 0..3 -> rows w*16..w*16+15
    int l = t & 63;
    int lr = l & 15;           // A row-in-tile / B col-in-tile / D col
    int lk = (l >> 4) * 8;     // k sub-block

    f32x4 acc[8];
#pragma unroll
    for (int i = 0; i < 8; ++i) acc[i] = (f32x4)(0.f);

#pragma unroll
    for (int ks = 0; ks < 4; ++ks) {
        f16x8 a = *(const f16x8*)&Al[(w * 16 + lr) * WTP + ks * 32 + lk];
#pragma unroll
        for (int tile = 0; tile < 8; ++tile) {
            f16x8 bh = *(const f16x8*)&Wl2[(tile * 16 + lr) * WTP + ks * 32 + lk];
            f16x8 bl = *(const f16x8*)&Wl2[DIM * WTP + (tile * 16 + lr) * WTP + ks * 32 + lk];
            acc[tile] = __builtin_amdgcn_mfma_f32_16x16x32_f16(a, bh, acc[tile], 0, 0, 0);
            acc[tile] = __builtin_amdgcn_mfma_f32_16x16x32_f16(a, bl, acc[tile], 0, 0, 0);
        }
    }

    long orow = row0 + w * 16 + (l >> 4) * 4;   // D: col=l&15, row=(l>>4)*4+i
#pragma unroll
    for (int tile = 0; tile < 8; ++tile) {
        int col = tile * 16 + lr;
        float b = bias[col];
#pragma unroll
        for (int i = 0; i < 4; ++i)
            out16[(orow + i) * DIM + col] = __float2half(acc[tile][i] + b);
    }
}

// ---------------- Aggregation + ReLU + BN partials (column-quarter q) -----
// Wave per dst node; 4 subgroups of 16 lanes stride the edge list (4 chains
// in flight); 16 lanes cover the quarter's 32 cols. Quarter table = 2.56MB
// -> L2-resident. partials: [q][block][64] (j<32 col sums, j>=32 sumsq).
__global__ __launch_bounds__(256) void k_agg(const __half* __restrict__ h16, const int* __restrict__ off,
                                             const int* __restrict__ elist, const float* __restrict__ dinv,
                                             float* __restrict__ hout, float* __restrict__ partials, int q) {
    __shared__ float colacc[64];
    if (threadIdx.x < 64) colacc[threadIdx.x] = 0.f;
    __syncthreads();

    const __half2* rows = (const __half2*)h16;   // 64 half2 per row
    int lane = threadIdx.x & 63;
    int h2i  = lane & 15;          // col-pair within quarter
    int esub = lane >> 4;          // 0..3 edge subgroup
    int wid = (blockIdx.x * 256 + threadIdx.x) >> 6;
    const int NW = AGG_BLOCKS * 4;
    int qb = q * 16;               // half2 base of this quarter
    float s0 = 0.f, s1 = 0.f, sq0 = 0.f, sq1 = 0.f;

    for (int i = wid; i < N_NODES; i += NW) {
        float di = dinv[i];
        float a0 = 0.f, a1 = 0.f;
        int e0 = off[i], e1 = off[i + 1];
#pragma unroll 2
        for (int e = e0 + esub; e < e1; e += 4) {
            int s = elist[e];
            float c = dinv[s] * di;
            float2 r = __half22float2(rows[(long)s * 64 + qb + h2i]);
            a0 = fmaf(r.x, c, a0);
            a1 = fmaf(r.y, c, a1);
        }
        a0 += __shfl_down(a0, 32); a1 += __shfl_down(a1, 32);
        a0 += __shfl_down(a0, 16); a1 += __shfl_down(a1, 16);
        if (esub == 0) {
            float2 rv = __half22float2(rows[(long)i * 64 + qb + h2i]);
            float selfc = di * di;
            a0 = fmaxf(fmaf(rv.x, selfc, a0), 0.f);
            a1 = fmaxf(fmaf(rv.y, selfc, a1), 0.f);
            ((float2*)(hout + (long)i * DIM))[qb + h2i] = make_float2(a0, a1);
            s0 += a0; sq0 += a0 * a0; s1 += a1; sq1 += a1 * a1;
        }
    }

    if (esub == 0) {
        atomicAdd(&colacc[2 * h2i],      s0);
        atomicAdd(&colacc[2 * h2i + 1],  s1);
        atomicAdd(&colacc[32 + 2 * h2i], sq0);
        atomicAdd(&colacc[33 + 2 * h2i], sq1);
    }
    __syncthreads();
    if (threadIdx.x < 64)
        partials[((size_t)q * AGG_BLOCKS + blockIdx.x) * 64 + threadIdx.x] = colacc[threadIdx.x];
}

// ---------------- BN stats -> affine a,c (8 blocks x 16 cols) ----------------
__global__ __launch_bounds__(1024) void k_stats(const float* __restrict__ partials,
                                                const float* __restrict__ gamma, const float* __restrict__ beta,
                                                float* __restrict__ ac) {
    __shared__ float ls[1024], lq[1024];
    int dd = threadIdx.x & 15;
    int seg = threadIdx.x >> 4;                    // 64 segments
    int d = blockIdx.x * 16 + dd;                  // 0..127
    int qq = d >> 5, j = d & 31;
    const float* base = partials + (size_t)qq * AGG_BLOCKS * 64;
    float s = 0.f, q = 0.f;
    for (int b = seg; b < AGG_BLOCKS; b += 64) {
        s += base[b * 64 + j];
        q += base[b * 64 + 32 + j];
    }
    ls[threadIdx.x] = s; lq[threadIdx.x] = q;
    __syncthreads();
    for (int off = 512; off >= 16; off >>= 1) {
        if (threadIdx.x < off) {
            ls[threadIdx.x] += ls[threadIdx.x + off];
            lq[threadIdx.x] += lq[threadIdx.x + off];
        }
        __syncthreads();
    }
    if (threadIdx.x < 16) {
        s = ls[threadIdx.x]; q = lq[threadIdx.x];
        float mean = s * (1.f / N_NODES);
        float var  = q * (1.f / N_NODES) - mean * mean;
        float a = gamma[d] * rsqrtf(var + BN_EPS);
        ac[d] = a;
        ac[DIM + d] = fmaf(-mean, a, beta[d]);
    }
}

// ---------------- Pool (applies last BN affine); 8 row-segments/block ----------------
__global__ __launch_bounds__(1024) void k_pool(const float* __restrict__ h, const float* __restrict__ ac,
                                               const int* __restrict__ goff, float* __restrict__ pooled) {
    __shared__ float red[1024];
    int g = blockIdx.x;
    int d = threadIdx.x & 127;
    int seg = threadIdx.x >> 7;                    // 8 segments
    int r0 = goff[g], r1 = goff[g + 1];
    float s = 0.f;
    for (int r = r0 + seg; r < r1; r += 8) s += h[(long)r * DIM + d];
    red[threadIdx.x] = s;
    __syncthreads();
    if (threadIdx.x < 512) red[threadIdx.x] += red[threadIdx.x + 512];
    __syncthreads();
    if (threadIdx.x < 256) red[threadIdx.x] += red[threadIdx.x + 256];
    __syncthreads();
    if (threadIdx.x < 128) {
        s = red[threadIdx.x] + red[threadIdx.x + 128];
        int n = r1 - r0;
        float a = ac[d], c = ac[DIM + d];
        float denom = (float)(n > 0 ? n : 1);
        pooled[g * DIM + d] = (a * s + c * (float)n) / denom;
    }
}

// ---------------- Final MLP ----------------
__global__ __launch_bounds__(64) void k_mlp(const float* __restrict__ pooled, const float* __restrict__ w1,
                                            const float* __restrict__ b1, const float* __restrict__ w2,
                                            const float* __restrict__ b2, float* __restrict__ out) {
    int g = blockIdx.x, j = threadIdx.x;
    const float* p = pooled + g * DIM;
    float h = b1[j];
#pragma unroll
    for (int k = 0; k < DIM; ++k) h = fmaf(p[k], w1[k * 64 + j], h);
    h = fmaxf(h, 0.f);
    float v = h * w2[j];
#pragma unroll
    for (int o = 32; o > 0; o >>= 1) v += __shfl_down(v, o);
    if (j == 0) out[g] = v + b2[0];
}

extern "C" void kernel_launch(void* const* d_in, const int* in_sizes, int n_in,
                              void* d_out, int out_size, void* d_ws, size_t ws_size,
                              hipStream_t stream) {
    const float* x      = (const float*)d_in[0];
    const int*   ei     = (const int*)d_in[1];
    const int*   batch  = (const int*)d_in[2];
    const float* Ws     = (const float*)d_in[3];
    const float* bs     = (const float*)d_in[4];
    const float* gammas = (const float*)d_in[5];
    const float* betas  = (const float*)d_in[6];
    const float* w1     = (const float*)d_in[7];
    const float* b1     = (const float*)d_in[8];
    const float* w2     = (const float*)d_in[9];
    const float* b2     = (const float*)d_in[10];
    float* out = (float*)d_out;

    char* p = (char*)d_ws;
    auto alloc = [&](size_t bytes) { void* r = (void*)p; p += (bytes + 255) & ~(size_t)255; return r; };
    int*    cnt      = (int*)alloc((size_t)N_NODES * 4);
    int*    off      = (int*)alloc((size_t)(N_NODES + 1) * 4);
    int*    pos      = (int*)alloc((size_t)N_NODES * 4);
    int*    goff     = (int*)alloc((size_t)(N_GRAPHS + 1) * 4);
    int*    blocksum = (int*)alloc((size_t)(SCAN_NB + 1) * 4);
    int*    blockoff = (int*)alloc((size_t)(SCAN_NB + 1) * 4);
    int*    elist    = (int*)alloc((size_t)N_EDGES * 4);
    float*  dinv     = (float*)alloc((size_t)N_NODES * 4);
    __half* wt       = (__half*)alloc((size_t)3 * 2 * DIM * WTP * 2);
    __half* h16      = (__half*)alloc((size_t)N_NODES * DIM * 2);
    float*  hB       = (float*)alloc((size_t)N_NODES * DIM * 4);
    float*  parts    = (float*)alloc((size_t)4 * AGG_BLOCKS * 64 * 4);
    float*  ac       = (float*)alloc(256 * 4);
    float*  pooled   = (float*)alloc((size_t)N_GRAPHS * DIM * 4);

    hipMemsetAsync(cnt, 0, (size_t)N_NODES * 4, stream);

    k_count_edges<<<(N_EDGES + 255) / 256, 256, 0, stream>>>(ei, cnt);
    k_boundaries<<<(N_NODES + 255) / 256, 256, 0, stream>>>(batch, goff);
    k_scan_blk<<<SCAN_NB, 1024, 0, stream>>>(cnt, off, blocksum);
    k_scan_tops<<<1, 64, 0, stream>>>(blocksum, blockoff);
    k_scan_fix<<<SCAN_NB, 1024, 0, stream>>>(cnt, blockoff, off, pos, dinv);
    k_fill<<<(N_EDGES + 255) / 256, 256, 0, stream>>>(ei, pos, elist);
    k_prepw<<<(3 * DIM * DIM + 255) / 256, 256, 0, stream>>>(Ws, wt);

    const float* cur_in = x;
    const float* cur_ac = nullptr;
    for (int l = 0; l < 3; ++l) {
        k_gemm<<<GEMM_NB, 256, 0, stream>>>(cur_in, wt + (size_t)l * 2 * DIM * WTP,
                                            bs + (size_t)l * DIM, cur_ac, h16);
        for (int q = 0; q < 4; ++q)
            k_agg<<<AGG_BLOCKS, 256, 0, stream>>>(h16, off, elist, dinv, hB, parts, q);
        k_stats<<<8, 1024, 0, stream>>>(parts, gammas + (size_t)l * DIM, betas + (size_t)l * DIM, ac);
        cur_in = hB;
        cur_ac = ac;
    }
    k_pool<<<N_GRAPHS, 1024, 0, stream>>>(hB, ac, goff, pooled);
    k_mlp<<<N_GRAPHS, 64, 0, stream>>>(pooled, w1, b1, w2, b2, out);
}

// Round 12
// 293.935 us; speedup vs baseline: 1.4867x; 1.4867x over previous
//
#include <hip/hip_runtime.h>
#include <hip/hip_fp16.h>

#define N_NODES 40000
#define N_EDGES 640000
#define DIM 128
#define N_GRAPHS 64
#define BN_EPS 1e-5f
#define AGG_BLOCKS 2048
#define SCAN_NB 40   // ceil(40000/1024)
#define GEMM_NB (N_NODES / 64)   // 625 blocks x 64 rows (exact)
#define WTP 136                  // padded k-stride for Wt / A tiles (halves)

typedef _Float16 f16x8 __attribute__((ext_vector_type(8)));
typedef float    f32x4 __attribute__((ext_vector_type(4)));

// ---------------- CSR build ----------------
// counts per dst; also records each edge's arrival rank (unique slot in dst's list)
__global__ __launch_bounds__(256) void k_count_edges(const int* __restrict__ ei, int* __restrict__ cnt,
                                                     int* __restrict__ rank) {
    int e = blockIdx.x * 256 + threadIdx.x;
    if (e < N_EDGES) rank[e] = atomicAdd(&cnt[ei[N_EDGES + e]], 1);
}

// batch is sorted: graph offsets are boundaries (no atomics).
__global__ __launch_bounds__(256) void k_boundaries(const int* __restrict__ batch, int* __restrict__ goff) {
    int n = blockIdx.x * 256 + threadIdx.x;
    if (n >= N_NODES) return;
    int b = batch[n];
    int bp = (n == 0) ? -1 : batch[n - 1];
    for (int g = bp + 1; g <= b; ++g) goff[g] = n;          // rare divergence
    if (n == N_NODES - 1)
        for (int g = b + 1; g <= N_GRAPHS; ++g) goff[g] = N_NODES;
}

// ---- 3-pass parallel exclusive scan of cnt -> off, plus dinv fill ----
__global__ __launch_bounds__(1024) void k_scan_blk(const int* __restrict__ cnt, int* __restrict__ off,
                                                   int* __restrict__ blocksum) {
    __shared__ int sums[1024];
    int i = blockIdx.x * 1024 + threadIdx.x;
    int v = (i < N_NODES) ? cnt[i] : 0;
    sums[threadIdx.x] = v;
    __syncthreads();
    for (int d = 1; d < 1024; d <<= 1) {
        int t = (threadIdx.x >= d) ? sums[threadIdx.x - d] : 0;
        __syncthreads();
        sums[threadIdx.x] += t;
        __syncthreads();
    }
    if (i < N_NODES) off[i] = sums[threadIdx.x] - v;        // exclusive within block
    if (threadIdx.x == 1023) blocksum[blockIdx.x] = sums[1023];
}

__global__ void k_scan_tops(const int* __restrict__ blocksum, int* __restrict__ blockoff) {
    if (threadIdx.x == 0) {
        int run = 0;
        for (int b = 0; b < SCAN_NB; ++b) { blockoff[b] = run; run += blocksum[b]; }
        blockoff[SCAN_NB] = run;
    }
}

__global__ __launch_bounds__(1024) void k_scan_fix(const int* __restrict__ cnt, const int* __restrict__ blockoff,
                                                   int* __restrict__ off, float* __restrict__ dinv) {
    int i = blockIdx.x * 1024 + threadIdx.x;
    if (i < N_NODES) {
        off[i] = off[i] + blockoff[blockIdx.x];
        dinv[i] = rsqrtf((float)(cnt[i] + 1));              // +1 self loop, always > 0
    }
    if (i == 0) off[N_NODES] = blockoff[SCAN_NB];
}

// no atomic: slot = off[dst] + rank[e]; one scattered 8B record {src, coef}
__global__ __launch_bounds__(256) void k_fill(const int* __restrict__ ei, const int* __restrict__ rank,
                                              const int* __restrict__ off, int2* __restrict__ erec,
                                              const float* __restrict__ dinv) {
    int e = blockIdx.x * 256 + threadIdx.x;
    if (e < N_EDGES) {
        int s = ei[e];                 // src row
        int d = ei[N_EDGES + e];       // dst row
        int p = off[d] + rank[e];
        float c = dinv[s] * dinv[d];
        erec[p] = make_int2(s, __float_as_int(c));
    }
}

// ---- W prep: per layer, transposed hi/lo fp16 split, padded [c][WTP] ----
// wt layout: [layer][2][128][WTP] halves; W = hi + lo to ~2^-22 rel.
__global__ __launch_bounds__(256) void k_prepw(const float* __restrict__ Ws, __half* __restrict__ wt) {
    int idx = blockIdx.x * 256 + threadIdx.x;        // 3*128*128
    if (idx >= 3 * DIM * DIM) return;
    int l = idx >> 14;
    int rem = idx & 16383;
    int k = rem >> 7;         // row of W
    int c = rem & 127;        // col of W
    float w = Ws[(size_t)l * DIM * DIM + k * DIM + c];
    __half hi = __float2half(w);
    __half lo = __float2half(w - __half2float(hi));
    size_t base = (size_t)l * 2 * DIM * WTP;
    wt[base + (size_t)c * WTP + k] = hi;
    wt[base + (size_t)DIM * WTP + (size_t)c * WTP + k] = lo;
}

// ---------------- GEMM via MFMA: out16 = fp16( affine(in) @ W + b ) -------
__global__ __launch_bounds__(256) void k_gemm(const float* __restrict__ in, const __half* __restrict__ wt2,
                                              const float* __restrict__ bias, const float* __restrict__ ac,
                                              __half* __restrict__ out16) {
    __shared__ __half Wl2[2 * DIM * WTP];   // hi then lo
    __shared__ __half Al[64 * WTP];
    int t = threadIdx.x;
    long row0 = (long)blockIdx.x * 64;

    {   // stage Wt hi+lo: 2*128*136 halves = 4352 float4
        const float4* src = (const float4*)wt2;
        float4* dst = (float4*)Wl2;
        for (int i = t; i < 4352; i += 256) dst[i] = src[i];
    }
    for (int i = t; i < 2048; i += 256) {   // A: 64 rows x 32 float4
        int r = i >> 5, k4 = i & 31;
        float4 v = ((const float4*)(in + (row0 + r) * DIM))[k4];
        if (ac) {
            int k = k4 * 4;
            v.x = fmaf(ac[k + 0], v.x, ac[DIM + k + 0]);
            v.y = fmaf(ac[k + 1], v.y, ac[DIM + k + 1]);
            v.z = fmaf(ac[k + 2], v.z, ac[DIM + k + 2]);
            v.w = fmaf(ac[k + 3], v.w, ac[DIM + k + 3]);
        }
        __half2* d = (__half2*)&Al[r * WTP + k4 * 4];
        d[0] = __floats2half2_rn(v.x, v.y);
        d[1] = __floats2half2_rn(v.z, v.w);
    }
    __syncthreads();

    int w = t >> 6;            // wave 0..3 -> rows w*16..w*16+15
    int l = t & 63;
    int lr = l & 15;           // A row-in-tile / B col-in-tile / D col
    int lk = (l >> 4) * 8;     // k sub-block

    f32x4 acc[8];
#pragma unroll
    for (int i = 0; i < 8; ++i) acc[i] = (f32x4)(0.f);

#pragma unroll
    for (int ks = 0; ks < 4; ++ks) {
        f16x8 a = *(const f16x8*)&Al[(w * 16 + lr) * WTP + ks * 32 + lk];
#pragma unroll
        for (int tile = 0; tile < 8; ++tile) {
            f16x8 bh = *(const f16x8*)&Wl2[(tile * 16 + lr) * WTP + ks * 32 + lk];
            f16x8 bl = *(const f16x8*)&Wl2[DIM * WTP + (tile * 16 + lr) * WTP + ks * 32 + lk];
            acc[tile] = __builtin_amdgcn_mfma_f32_16x16x32_f16(a, bh, acc[tile], 0, 0, 0);
            acc[tile] = __builtin_amdgcn_mfma_f32_16x16x32_f16(a, bl, acc[tile], 0, 0, 0);
        }
    }

    long orow = row0 + w * 16 + (l >> 4) * 4;   // D: col=l&15, row=(l>>4)*4+i
#pragma unroll
    for (int tile = 0; tile < 8; ++tile) {
        int col = tile * 16 + lr;
        float b = bias[col];
#pragma unroll
        for (int i = 0; i < 4; ++i)
            out16[(orow + i) * DIM + col] = __float2half(acc[tile][i] + b);
    }
}

// ---------------- Aggregation + ReLU + BN partial stats (R10 form) --------
__global__ __launch_bounds__(256) void k_agg(const __half* __restrict__ h16, const int* __restrict__ off,
                                             const int2* __restrict__ erec,
                                             const float* __restrict__ dinv, float* __restrict__ hout,
                                             float* __restrict__ partials) {
    __shared__ float colacc[256];
    colacc[threadIdx.x] = 0.f;
    __syncthreads();

    const __half2* rows = (const __half2*)h16;   // 64 half2 per row
    int lane = threadIdx.x & 63;
    int wid = (blockIdx.x * 256 + threadIdx.x) >> 6;
    const int NW = AGG_BLOCKS * 4;
    float s0 = 0.f, s1 = 0.f, q0 = 0.f, q1 = 0.f;

    for (int i = wid; i < N_NODES; i += NW) {
        float di = dinv[i];
        float selfc = di * di;
        float2 rv = __half22float2(rows[(long)i * 64 + lane]);
        float a0 = rv.x * selfc, a1 = rv.y * selfc;
        int e  = off[i];
        int e1 = off[i + 1];
#pragma unroll 4
        for (; e < e1; ++e) {
            int2 rec = erec[e];
            float c = __int_as_float(rec.y);
            float2 r = __half22float2(rows[(long)rec.x * 64 + lane]);
            a0 = fmaf(r.x, c, a0);
            a1 = fmaf(r.y, c, a1);
        }
        a0 = fmaxf(a0, 0.f);
        a1 = fmaxf(a1, 0.f);
        ((float2*)(hout + (long)i * DIM))[lane] = make_float2(a0, a1);
        s0 += a0; q0 += a0 * a0; s1 += a1; q1 += a1 * a1;
    }

    // partials layout: [0..127] col sums, [128..255] col sumsq (true col idx)
    atomicAdd(&colacc[2 * lane],           s0);
    atomicAdd(&colacc[2 * lane + 1],       s1);
    atomicAdd(&colacc[128 + 2 * lane],     q0);
    atomicAdd(&colacc[128 + 2 * lane + 1], q1);
    __syncthreads();
    partials[(long)blockIdx.x * 256 + threadIdx.x] = colacc[threadIdx.x];
}

// ---------------- BN stats -> affine a,c (8 blocks x 16 cols) ----------------
__global__ __launch_bounds__(1024) void k_stats(const float* __restrict__ partials,
                                                const float* __restrict__ gamma, const float* __restrict__ beta,
                                                float* __restrict__ ac) {
    __shared__ float ls[1024], lq[1024];
    int dd = threadIdx.x & 15;
    int seg = threadIdx.x >> 4;                    // 64 segments
    int d = blockIdx.x * 16 + dd;
    float s = 0.f, q = 0.f;
    for (int b = seg; b < AGG_BLOCKS; b += 64) {
        s += partials[b * 256 + d];
        q += partials[b * 256 + 128 + d];
    }
    ls[threadIdx.x] = s; lq[threadIdx.x] = q;
    __syncthreads();
    for (int off = 512; off >= 16; off >>= 1) {
        if (threadIdx.x < off) {
            ls[threadIdx.x] += ls[threadIdx.x + off];
            lq[threadIdx.x] += lq[threadIdx.x + off];
        }
        __syncthreads();
    }
    if (threadIdx.x < 16) {
        s = ls[threadIdx.x]; q = lq[threadIdx.x];
        float mean = s * (1.f / N_NODES);
        float var  = q * (1.f / N_NODES) - mean * mean;
        float a = gamma[d] * rsqrtf(var + BN_EPS);
        ac[d] = a;
        ac[DIM + d] = fmaf(-mean, a, beta[d]);
    }
}

// ---------------- Pool (applies last BN affine); 8 row-segments/block ----------------
__global__ __launch_bounds__(1024) void k_pool(const float* __restrict__ h, const float* __restrict__ ac,
                                               const int* __restrict__ goff, float* __restrict__ pooled) {
    __shared__ float red[1024];
    int g = blockIdx.x;
    int d = threadIdx.x & 127;
    int seg = threadIdx.x >> 7;                    // 8 segments
    int r0 = goff[g], r1 = goff[g + 1];
    float s = 0.f;
    for (int r = r0 + seg; r < r1; r += 8) s += h[(long)r * DIM + d];
    red[threadIdx.x] = s;
    __syncthreads();
    if (threadIdx.x < 512) red[threadIdx.x] += red[threadIdx.x + 512];
    __syncthreads();
    if (threadIdx.x < 256) red[threadIdx.x] += red[threadIdx.x + 256];
    __syncthreads();
    if (threadIdx.x < 128) {
        s = red[threadIdx.x] + red[threadIdx.x + 128];
        int n = r1 - r0;
        float a = ac[d], c = ac[DIM + d];
        float denom = (float)(n > 0 ? n : 1);
        pooled[g * DIM + d] = (a * s + c * (float)n) / denom;
    }
}

// ---------------- Final MLP ----------------
__global__ __launch_bounds__(64) void k_mlp(const float* __restrict__ pooled, const float* __restrict__ w1,
                                            const float* __restrict__ b1, const float* __restrict__ w2,
                                            const float* __restrict__ b2, float* __restrict__ out) {
    int g = blockIdx.x, j = threadIdx.x;
    const float* p = pooled + g * DIM;
    float h = b1[j];
#pragma unroll
    for (int k = 0; k < DIM; ++k) h = fmaf(p[k], w1[k * 64 + j], h);
    h = fmaxf(h, 0.f);
    float v = h * w2[j];
#pragma unroll
    for (int o = 32; o > 0; o >>= 1) v += __shfl_down(v, o);
    if (j == 0) out[g] = v + b2[0];
}

extern "C" void kernel_launch(void* const* d_in, const int* in_sizes, int n_in,
                              void* d_out, int out_size, void* d_ws, size_t ws_size,
                              hipStream_t stream) {
    const float* x      = (const float*)d_in[0];
    const int*   ei     = (const int*)d_in[1];
    const int*   batch  = (const int*)d_in[2];
    const float* Ws     = (const float*)d_in[3];
    const float* bs     = (const float*)d_in[4];
    const float* gammas = (const float*)d_in[5];
    const float* betas  = (const float*)d_in[6];
    const float* w1     = (const float*)d_in[7];
    const float* b1     = (const float*)d_in[8];
    const float* w2     = (const float*)d_in[9];
    const float* b2     = (const float*)d_in[10];
    float* out = (float*)d_out;

    char* p = (char*)d_ws;
    auto alloc = [&](size_t bytes) { void* r = (void*)p; p += (bytes + 255) & ~(size_t)255; return r; };
    int*    cnt      = (int*)alloc((size_t)N_NODES * 4);
    int*    off      = (int*)alloc((size_t)(N_NODES + 1) * 4);
    int*    rank     = (int*)alloc((size_t)N_EDGES * 4);
    int*    goff     = (int*)alloc((size_t)(N_GRAPHS + 1) * 4);
    int*    blocksum = (int*)alloc((size_t)(SCAN_NB + 1) * 4);
    int*    blockoff = (int*)alloc((size_t)(SCAN_NB + 1) * 4);
    int2*   erec     = (int2*)alloc((size_t)N_EDGES * 8);
    float*  dinv     = (float*)alloc((size_t)N_NODES * 4);
    __half* wt       = (__half*)alloc((size_t)3 * 2 * DIM * WTP * 2);
    __half* h16      = (__half*)alloc((size_t)N_NODES * DIM * 2);
    float*  hB       = (float*)alloc((size_t)N_NODES * DIM * 4);
    float*  parts    = (float*)alloc((size_t)AGG_BLOCKS * 256 * 4);
    float*  ac       = (float*)alloc(256 * 4);
    float*  pooled   = (float*)alloc((size_t)N_GRAPHS * DIM * 4);

    hipMemsetAsync(cnt, 0, (size_t)N_NODES * 4, stream);

    k_count_edges<<<(N_EDGES + 255) / 256, 256, 0, stream>>>(ei, cnt, rank);
    k_boundaries<<<(N_NODES + 255) / 256, 256, 0, stream>>>(batch, goff);
    k_scan_blk<<<SCAN_NB, 1024, 0, stream>>>(cnt, off, blocksum);
    k_scan_tops<<<1, 64, 0, stream>>>(blocksum, blockoff);
    k_scan_fix<<<SCAN_NB, 1024, 0, stream>>>(cnt, blockoff, off, dinv);
    k_fill<<<(N_EDGES + 255) / 256, 256, 0, stream>>>(ei, rank, off, erec, dinv);
    k_prepw<<<(3 * DIM * DIM + 255) / 256, 256, 0, stream>>>(Ws, wt);

    const float* cur_in = x;
    const float* cur_ac = nullptr;
    for (int l = 0; l < 3; ++l) {
        k_gemm<<<GEMM_NB, 256, 0, stream>>>(cur_in, wt + (size_t)l * 2 * DIM * WTP,
                                            bs + (size_t)l * DIM, cur_ac, h16);
        k_agg<<<AGG_BLOCKS, 256, 0, stream>>>(h16, off, erec, dinv, hB, parts);
        k_stats<<<8, 1024, 0, stream>>>(parts, gammas + (size_t)l * DIM, betas + (size_t)l * DIM, ac);
        cur_in = hB;
        cur_ac = ac;
    }
    k_pool<<<N_GRAPHS, 1024, 0, stream>>>(hB, ac, goff, pooled);
    k_mlp<<<N_GRAPHS, 64, 0, stream>>>(pooled, w1, b1, w2, b2, out);
}

// Round 13
// 280.772 us; speedup vs baseline: 1.5564x; 1.0469x over previous
//
#include <hip/hip_runtime.h>
#include <hip/hip_fp16.h>

#define N_NODES 40000
#define N_EDGES 640000
#define DIM 128
#define N_GRAPHS 64
#define BN_EPS 1e-5f
#define AGG_BLOCKS 2048
#define SCAN_NB 40   // ceil(40000/1024)
#define GEMM_NB (N_NODES / 64)   // 625 blocks x 64 rows (exact)
#define WTP 136                  // padded k-stride for Wt / A tiles (halves)

typedef _Float16 f16x8 __attribute__((ext_vector_type(8)));
typedef float    f32x4 __attribute__((ext_vector_type(4)));

// ---------------- CSR build ----------------
// counts per dst; also records each edge's arrival rank (unique slot in dst's list)
__global__ __launch_bounds__(256) void k_count_edges(const int* __restrict__ ei, int* __restrict__ cnt,
                                                     int* __restrict__ rank) {
    int e = blockIdx.x * 256 + threadIdx.x;
    if (e < N_EDGES) rank[e] = atomicAdd(&cnt[ei[N_EDGES + e]], 1);
}

// ---- 2-pass parallel exclusive scan of cnt -> off, + dinv + graph bounds ----
__global__ __launch_bounds__(1024) void k_scan_blk(const int* __restrict__ cnt, int* __restrict__ off,
                                                   int* __restrict__ blocksum) {
    __shared__ int sums[1024];
    int i = blockIdx.x * 1024 + threadIdx.x;
    int v = (i < N_NODES) ? cnt[i] : 0;
    sums[threadIdx.x] = v;
    __syncthreads();
    for (int d = 1; d < 1024; d <<= 1) {
        int t = (threadIdx.x >= d) ? sums[threadIdx.x - d] : 0;
        __syncthreads();
        sums[threadIdx.x] += t;
        __syncthreads();
    }
    if (i < N_NODES) off[i] = sums[threadIdx.x] - v;        // exclusive within block
    if (threadIdx.x == 1023) blocksum[blockIdx.x] = sums[1023];
}

// adds block offsets (each block recomputes the tiny 40-prefix locally),
// fills dinv, and writes sorted-batch graph boundaries.
__global__ __launch_bounds__(1024) void k_scan_fix(const int* __restrict__ cnt, const int* __restrict__ blocksum,
                                                   int* __restrict__ off, float* __restrict__ dinv,
                                                   const int* __restrict__ batch, int* __restrict__ goff) {
    __shared__ int bo[2];
    if (threadIdx.x == 0) {
        int run = 0, tot = 0;
        for (int b = 0; b < SCAN_NB; ++b) {
            int v = blocksum[b];
            if (b < (int)blockIdx.x) run += v;
            tot += v;
        }
        bo[0] = run; bo[1] = tot;
    }
    __syncthreads();
    int i = blockIdx.x * 1024 + threadIdx.x;
    if (i < N_NODES) {
        off[i] += bo[0];
        dinv[i] = rsqrtf((float)(cnt[i] + 1));              // +1 self loop, always > 0
        int b = batch[i];
        int bp = (i == 0) ? -1 : batch[i - 1];
        for (int g = bp + 1; g <= b; ++g) goff[g] = i;      // rare divergence
        if (i == N_NODES - 1)
            for (int g = b + 1; g <= N_GRAPHS; ++g) goff[g] = N_NODES;
    }
    if (i == 0) off[N_NODES] = bo[1];
}

// no atomic: slot = off[dst] + rank[e]; one scattered 8B record {src, coef}
__global__ __launch_bounds__(256) void k_fill(const int* __restrict__ ei, const int* __restrict__ rank,
                                              const int* __restrict__ off, int2* __restrict__ erec,
                                              const float* __restrict__ dinv) {
    int e = blockIdx.x * 256 + threadIdx.x;
    if (e < N_EDGES) {
        int s = ei[e];                 // src row
        int d = ei[N_EDGES + e];       // dst row
        int p = off[d] + rank[e];
        float c = dinv[s] * dinv[d];
        erec[p] = make_int2(s, __float_as_int(c));
    }
}

// ---- W prep: per layer, transposed hi/lo fp16 split, padded [c][WTP] ----
__global__ __launch_bounds__(256) void k_prepw(const float* __restrict__ Ws, __half* __restrict__ wt) {
    int idx = blockIdx.x * 256 + threadIdx.x;        // 3*128*128
    if (idx >= 3 * DIM * DIM) return;
    int l = idx >> 14;
    int rem = idx & 16383;
    int k = rem >> 7;         // row of W
    int c = rem & 127;        // col of W
    float w = Ws[(size_t)l * DIM * DIM + k * DIM + c];
    __half hi = __float2half(w);
    __half lo = __float2half(w - __half2float(hi));
    size_t base = (size_t)l * 2 * DIM * WTP;
    wt[base + (size_t)c * WTP + k] = hi;
    wt[base + (size_t)DIM * WTP + (size_t)c * WTP + k] = lo;
}

// ---------------- GEMM core (MFMA, shared by both input variants) ---------
__device__ __forceinline__ void gemm_core(const __half* __restrict__ wt2, const float* __restrict__ bias,
                                          __half* __restrict__ out16, __half* Wl2, __half* Al,
                                          int t, long row0) {
    {   // stage Wt hi+lo: 2*128*136 halves = 4352 float4
        const float4* src = (const float4*)wt2;
        float4* dst = (float4*)Wl2;
        for (int i = t; i < 4352; i += 256) dst[i] = src[i];
    }
    __syncthreads();

    int w = t >> 6;            // wave 0..3 -> rows w*16..w*16+15
    int l = t & 63;
    int lr = l & 15;           // A row-in-tile / B col-in-tile / D col
    int lk = (l >> 4) * 8;     // k sub-block

    f32x4 acc[8];
#pragma unroll
    for (int i = 0; i < 8; ++i) acc[i] = (f32x4)(0.f);

#pragma unroll
    for (int ks = 0; ks < 4; ++ks) {
        f16x8 a = *(const f16x8*)&Al[(w * 16 + lr) * WTP + ks * 32 + lk];
#pragma unroll
        for (int tile = 0; tile < 8; ++tile) {
            f16x8 bh = *(const f16x8*)&Wl2[(tile * 16 + lr) * WTP + ks * 32 + lk];
            f16x8 bl = *(const f16x8*)&Wl2[DIM * WTP + (tile * 16 + lr) * WTP + ks * 32 + lk];
            acc[tile] = __builtin_amdgcn_mfma_f32_16x16x32_f16(a, bh, acc[tile], 0, 0, 0);
            acc[tile] = __builtin_amdgcn_mfma_f32_16x16x32_f16(a, bl, acc[tile], 0, 0, 0);
        }
    }

    long orow = row0 + w * 16 + (l >> 4) * 4;   // D: col=l&15, row=(l>>4)*4+i
#pragma unroll
    for (int tile = 0; tile < 8; ++tile) {
        int col = tile * 16 + lr;
        float b = bias[col];
#pragma unroll
        for (int i = 0; i < 4; ++i)
            out16[(orow + i) * DIM + col] = __float2half(acc[tile][i] + b);
    }
}

// layer 0: fp32 input, no affine
__global__ __launch_bounds__(256) void k_gemm_f32(const float* __restrict__ in, const __half* __restrict__ wt2,
                                                  const float* __restrict__ bias, __half* __restrict__ out16) {
    __shared__ __half Wl2[2 * DIM * WTP];
    __shared__ __half Al[64 * WTP];
    int t = threadIdx.x;
    long row0 = (long)blockIdx.x * 64;
    for (int i = t; i < 2048; i += 256) {   // 64 rows x 32 float4
        int r = i >> 5, k4 = i & 31;
        float4 v = ((const float4*)(in + (row0 + r) * DIM))[k4];
        __half2* d = (__half2*)&Al[r * WTP + k4 * 4];
        d[0] = __floats2half2_rn(v.x, v.y);
        d[1] = __floats2half2_rn(v.z, v.w);
    }
    gemm_core(wt2, bias, out16, Wl2, Al, t, row0);
}

// layers 1,2: fp16 input with BN affine
__global__ __launch_bounds__(256) void k_gemm_f16(const __half* __restrict__ in, const __half* __restrict__ wt2,
                                                  const float* __restrict__ bias, const float* __restrict__ ac,
                                                  __half* __restrict__ out16) {
    __shared__ __half Wl2[2 * DIM * WTP];
    __shared__ __half Al[64 * WTP];
    int t = threadIdx.x;
    long row0 = (long)blockIdx.x * 64;
    for (int i = t; i < 1024; i += 256) {   // 64 rows x 16 chunks of 8 halves
        int r = i >> 4, k8 = i & 15;
        const __half2* src = (const __half2*)(in + (row0 + r) * DIM + k8 * 8);
        int k = k8 * 8;
        float2 f0 = __half22float2(src[0]);
        float2 f1 = __half22float2(src[1]);
        float2 f2 = __half22float2(src[2]);
        float2 f3 = __half22float2(src[3]);
        f0.x = fmaf(ac[k + 0], f0.x, ac[DIM + k + 0]); f0.y = fmaf(ac[k + 1], f0.y, ac[DIM + k + 1]);
        f1.x = fmaf(ac[k + 2], f1.x, ac[DIM + k + 2]); f1.y = fmaf(ac[k + 3], f1.y, ac[DIM + k + 3]);
        f2.x = fmaf(ac[k + 4], f2.x, ac[DIM + k + 4]); f2.y = fmaf(ac[k + 5], f2.y, ac[DIM + k + 5]);
        f3.x = fmaf(ac[k + 6], f3.x, ac[DIM + k + 6]); f3.y = fmaf(ac[k + 7], f3.y, ac[DIM + k + 7]);
        __half2* d = (__half2*)&Al[r * WTP + k];
        d[0] = __floats2half2_rn(f0.x, f0.y);
        d[1] = __floats2half2_rn(f1.x, f1.y);
        d[2] = __floats2half2_rn(f2.x, f2.y);
        d[3] = __floats2half2_rn(f3.x, f3.y);
    }
    gemm_core(wt2, bias, out16, Wl2, Al, t, row0);
}

// ---------------- Aggregation + ReLU + BN partial stats -------------------
// fp16 gather table in, fp16 v-table out (stats computed pre-rounding).
__global__ __launch_bounds__(256) void k_agg(const __half* __restrict__ h16, const int* __restrict__ off,
                                             const int2* __restrict__ erec,
                                             const float* __restrict__ dinv, __half* __restrict__ hout,
                                             float* __restrict__ partials) {
    __shared__ float colacc[256];
    colacc[threadIdx.x] = 0.f;
    __syncthreads();

    const __half2* rows = (const __half2*)h16;   // 64 half2 per row
    int lane = threadIdx.x & 63;
    int wid = (blockIdx.x * 256 + threadIdx.x) >> 6;
    const int NW = AGG_BLOCKS * 4;
    float s0 = 0.f, s1 = 0.f, q0 = 0.f, q1 = 0.f;

    for (int i = wid; i < N_NODES; i += NW) {
        float di = dinv[i];
        float selfc = di * di;
        float2 rv = __half22float2(rows[(long)i * 64 + lane]);
        float a0 = rv.x * selfc, a1 = rv.y * selfc;
        int e  = off[i];
        int e1 = off[i + 1];
#pragma unroll 4
        for (; e < e1; ++e) {
            int2 rec = erec[e];
            float c = __int_as_float(rec.y);
            float2 r = __half22float2(rows[(long)rec.x * 64 + lane]);
            a0 = fmaf(r.x, c, a0);
            a1 = fmaf(r.y, c, a1);
        }
        a0 = fmaxf(a0, 0.f);
        a1 = fmaxf(a1, 0.f);
        ((__half2*)(hout + (long)i * DIM))[lane] = __floats2half2_rn(a0, a1);
        s0 += a0; q0 += a0 * a0; s1 += a1; q1 += a1 * a1;
    }

    // partials layout: [0..127] col sums, [128..255] col sumsq (true col idx)
    atomicAdd(&colacc[2 * lane],           s0);
    atomicAdd(&colacc[2 * lane + 1],       s1);
    atomicAdd(&colacc[128 + 2 * lane],     q0);
    atomicAdd(&colacc[128 + 2 * lane + 1], q1);
    __syncthreads();
    partials[(long)blockIdx.x * 256 + threadIdx.x] = colacc[threadIdx.x];
}

// ---------------- BN stats -> affine a,c (8 blocks x 16 cols) ----------------
__global__ __launch_bounds__(1024) void k_stats(const float* __restrict__ partials,
                                                const float* __restrict__ gamma, const float* __restrict__ beta,
                                                float* __restrict__ ac) {
    __shared__ float ls[1024], lq[1024];
    int dd = threadIdx.x & 15;
    int seg = threadIdx.x >> 4;                    // 64 segments
    int d = blockIdx.x * 16 + dd;
    float s = 0.f, q = 0.f;
    for (int b = seg; b < AGG_BLOCKS; b += 64) {
        s += partials[b * 256 + d];
        q += partials[b * 256 + 128 + d];
    }
    ls[threadIdx.x] = s; lq[threadIdx.x] = q;
    __syncthreads();
    for (int off = 512; off >= 16; off >>= 1) {
        if (threadIdx.x < off) {
            ls[threadIdx.x] += ls[threadIdx.x + off];
            lq[threadIdx.x] += lq[threadIdx.x + off];
        }
        __syncthreads();
    }
    if (threadIdx.x < 16) {
        s = ls[threadIdx.x]; q = lq[threadIdx.x];
        float mean = s * (1.f / N_NODES);
        float var  = q * (1.f / N_NODES) - mean * mean;
        float a = gamma[d] * rsqrtf(var + BN_EPS);
        ac[d] = a;
        ac[DIM + d] = fmaf(-mean, a, beta[d]);
    }
}

// ---------------- Pool (applies last BN affine); half2, 16 segments -------
__global__ __launch_bounds__(1024) void k_pool(const __half* __restrict__ h, const float* __restrict__ ac,
                                               const int* __restrict__ goff, float* __restrict__ pooled) {
    __shared__ float2 red[1024];
    int g = blockIdx.x;
    int d2 = threadIdx.x & 63;                     // col pair
    int seg = threadIdx.x >> 6;                    // 16 segments
    int r0 = goff[g], r1 = goff[g + 1];
    const __half2* rows = (const __half2*)h;
    float s0 = 0.f, s1 = 0.f;
    for (int r = r0 + seg; r < r1; r += 16) {
        float2 v = __half22float2(rows[(long)r * 64 + d2]);
        s0 += v.x; s1 += v.y;
    }
    red[threadIdx.x] = make_float2(s0, s1);
    __syncthreads();
    for (int off = 512; off >= 64; off >>= 1) {
        if (threadIdx.x < off) {
            red[threadIdx.x].x += red[threadIdx.x + off].x;
            red[threadIdx.x].y += red[threadIdx.x + off].y;
        }
        __syncthreads();
    }
    if (threadIdx.x < 64) {
        float2 s = red[threadIdx.x];
        int n = r1 - r0;
        float fn = (float)n;
        float denom = (float)(n > 0 ? n : 1);
        int d = 2 * threadIdx.x;
        pooled[g * DIM + d]     = (ac[d] * s.x     + ac[DIM + d] * fn)     / denom;
        pooled[g * DIM + d + 1] = (ac[d + 1] * s.y + ac[DIM + d + 1] * fn) / denom;
    }
}

// ---------------- Final MLP ----------------
__global__ __launch_bounds__(64) void k_mlp(const float* __restrict__ pooled, const float* __restrict__ w1,
                                            const float* __restrict__ b1, const float* __restrict__ w2,
                                            const float* __restrict__ b2, float* __restrict__ out) {
    int g = blockIdx.x, j = threadIdx.x;
    const float* p = pooled + g * DIM;
    float h = b1[j];
#pragma unroll
    for (int k = 0; k < DIM; ++k) h = fmaf(p[k], w1[k * 64 + j], h);
    h = fmaxf(h, 0.f);
    float v = h * w2[j];
#pragma unroll
    for (int o = 32; o > 0; o >>= 1) v += __shfl_down(v, o);
    if (j == 0) out[g] = v + b2[0];
}

extern "C" void kernel_launch(void* const* d_in, const int* in_sizes, int n_in,
                              void* d_out, int out_size, void* d_ws, size_t ws_size,
                              hipStream_t stream) {
    const float* x      = (const float*)d_in[0];
    const int*   ei     = (const int*)d_in[1];
    const int*   batch  = (const int*)d_in[2];
    const float* Ws     = (const float*)d_in[3];
    const float* bs     = (const float*)d_in[4];
    const float* gammas = (const float*)d_in[5];
    const float* betas  = (const float*)d_in[6];
    const float* w1     = (const float*)d_in[7];
    const float* b1     = (const float*)d_in[8];
    const float* w2     = (const float*)d_in[9];
    const float* b2     = (const float*)d_in[10];
    float* out = (float*)d_out;

    char* p = (char*)d_ws;
    auto alloc = [&](size_t bytes) { void* r = (void*)p; p += (bytes + 255) & ~(size_t)255; return r; };
    int*    cnt      = (int*)alloc((size_t)N_NODES * 4);
    int*    off      = (int*)alloc((size_t)(N_NODES + 1) * 4);
    int*    rank     = (int*)alloc((size_t)N_EDGES * 4);
    int*    goff     = (int*)alloc((size_t)(N_GRAPHS + 1) * 4);
    int*    blocksum = (int*)alloc((size_t)(SCAN_NB + 1) * 4);
    int2*   erec     = (int2*)alloc((size_t)N_EDGES * 8);
    float*  dinv     = (float*)alloc((size_t)N_NODES * 4);
    __half* wt       = (__half*)alloc((size_t)3 * 2 * DIM * WTP * 2);
    __half* h16      = (__half*)alloc((size_t)N_NODES * DIM * 2);
    __half* v16      = (__half*)alloc((size_t)N_NODES * DIM * 2);
    float*  parts    = (float*)alloc((size_t)AGG_BLOCKS * 256 * 4);
    float*  ac       = (float*)alloc(256 * 4);
    float*  pooled   = (float*)alloc((size_t)N_GRAPHS * DIM * 4);

    hipMemsetAsync(cnt, 0, (size_t)N_NODES * 4, stream);

    k_count_edges<<<(N_EDGES + 255) / 256, 256, 0, stream>>>(ei, cnt, rank);
    k_scan_blk<<<SCAN_NB, 1024, 0, stream>>>(cnt, off, blocksum);
    k_scan_fix<<<SCAN_NB, 1024, 0, stream>>>(cnt, blocksum, off, dinv, batch, goff);
    k_fill<<<(N_EDGES + 255) / 256, 256, 0, stream>>>(ei, rank, off, erec, dinv);
    k_prepw<<<(3 * DIM * DIM + 255) / 256, 256, 0, stream>>>(Ws, wt);

    for (int l = 0; l < 3; ++l) {
        if (l == 0)
            k_gemm_f32<<<GEMM_NB, 256, 0, stream>>>(x, wt, bs, h16);
        else
            k_gemm_f16<<<GEMM_NB, 256, 0, stream>>>(v16, wt + (size_t)l * 2 * DIM * WTP,
                                                    bs + (size_t)l * DIM, ac, h16);
        k_agg<<<AGG_BLOCKS, 256, 0, stream>>>(h16, off, erec, dinv, v16, parts);
        k_stats<<<8, 1024, 0, stream>>>(parts, gammas + (size_t)l * DIM, betas + (size_t)l * DIM, ac);
    }
    k_pool<<<N_GRAPHS, 1024, 0, stream>>>(v16, ac, goff, pooled);
    k_mlp<<<N_GRAPHS, 64, 0, stream>>>(pooled, w1, b1, w2, b2, out);
}

// Round 14
// 276.255 us; speedup vs baseline: 1.5818x; 1.0164x over previous
//
#include <hip/hip_runtime.h>
#include <hip/hip_fp16.h>

#define N_NODES 40000
#define N_EDGES 640000
#define DIM 128
#define N_GRAPHS 64
#define BN_EPS 1e-5f
#define AGG_BLOCKS 2048
#define SCAN_NB 40   // ceil(40000/1024)
#define GEMM_NB (N_NODES / 64)   // 625 blocks x 64 rows (exact)
#define WTP 136                  // padded k-stride for Wt / A tiles (halves)

typedef _Float16 f16x8 __attribute__((ext_vector_type(8)));
typedef float    f32x4 __attribute__((ext_vector_type(4)));

// ---------------- CSR build ----------------
// counts per dst; also records each edge's arrival rank (unique slot in dst's list)
__global__ __launch_bounds__(256) void k_count_edges(const int* __restrict__ ei, int* __restrict__ cnt,
                                                     int* __restrict__ rank) {
    int e = blockIdx.x * 256 + threadIdx.x;
    if (e < N_EDGES) rank[e] = atomicAdd(&cnt[ei[N_EDGES + e]], 1);
}

// ---- 2-pass parallel exclusive scan of cnt -> off, + dinv + graph bounds ----
__global__ __launch_bounds__(1024) void k_scan_blk(const int* __restrict__ cnt, int* __restrict__ off,
                                                   int* __restrict__ blocksum) {
    __shared__ int sums[1024];
    int i = blockIdx.x * 1024 + threadIdx.x;
    int v = (i < N_NODES) ? cnt[i] : 0;
    sums[threadIdx.x] = v;
    __syncthreads();
    for (int d = 1; d < 1024; d <<= 1) {
        int t = (threadIdx.x >= d) ? sums[threadIdx.x - d] : 0;
        __syncthreads();
        sums[threadIdx.x] += t;
        __syncthreads();
    }
    if (i < N_NODES) off[i] = sums[threadIdx.x] - v;        // exclusive within block
    if (threadIdx.x == 1023) blocksum[blockIdx.x] = sums[1023];
}

// adds block offsets (each block recomputes the tiny 40-prefix locally),
// fills dinv, and writes sorted-batch graph boundaries.
__global__ __launch_bounds__(1024) void k_scan_fix(const int* __restrict__ cnt, const int* __restrict__ blocksum,
                                                   int* __restrict__ off, float* __restrict__ dinv,
                                                   const int* __restrict__ batch, int* __restrict__ goff) {
    __shared__ int bo[2];
    if (threadIdx.x == 0) {
        int run = 0, tot = 0;
        for (int b = 0; b < SCAN_NB; ++b) {
            int v = blocksum[b];
            if (b < (int)blockIdx.x) run += v;
            tot += v;
        }
        bo[0] = run; bo[1] = tot;
    }
    __syncthreads();
    int i = blockIdx.x * 1024 + threadIdx.x;
    if (i < N_NODES) {
        off[i] += bo[0];
        dinv[i] = rsqrtf((float)(cnt[i] + 1));              // +1 self loop, always > 0
        int b = batch[i];
        int bp = (i == 0) ? -1 : batch[i - 1];
        for (int g = bp + 1; g <= b; ++g) goff[g] = i;      // rare divergence
        if (i == N_NODES - 1)
            for (int g = b + 1; g <= N_GRAPHS; ++g) goff[g] = N_NODES;
    }
    if (i == 0) off[N_NODES] = bo[1];
}

// no atomic: slot = off[dst] + rank[e]; scatter 4B src index only
// (coef is recomputed in k_agg as dinv[s]*dinv[d] -- bit-identical product)
__global__ __launch_bounds__(256) void k_fill(const int* __restrict__ ei, const int* __restrict__ rank,
                                              const int* __restrict__ off, int* __restrict__ elist) {
    int e = blockIdx.x * 256 + threadIdx.x;
    if (e < N_EDGES) {
        int s = ei[e];                 // src row
        int d = ei[N_EDGES + e];       // dst row
        elist[off[d] + rank[e]] = s;
    }
}

// ---- W prep: per layer, transposed hi/lo fp16 split, padded [c][WTP] ----
__global__ __launch_bounds__(256) void k_prepw(const float* __restrict__ Ws, __half* __restrict__ wt) {
    int idx = blockIdx.x * 256 + threadIdx.x;        // 3*128*128
    if (idx >= 3 * DIM * DIM) return;
    int l = idx >> 14;
    int rem = idx & 16383;
    int k = rem >> 7;         // row of W
    int c = rem & 127;        // col of W
    float w = Ws[(size_t)l * DIM * DIM + k * DIM + c];
    __half hi = __float2half(w);
    __half lo = __float2half(w - __half2float(hi));
    size_t base = (size_t)l * 2 * DIM * WTP;
    wt[base + (size_t)c * WTP + k] = hi;
    wt[base + (size_t)DIM * WTP + (size_t)c * WTP + k] = lo;
}

// ---------------- GEMM core (MFMA, shared by both input variants) ---------
__device__ __forceinline__ void gemm_core(const __half* __restrict__ wt2, const float* __restrict__ bias,
                                          __half* __restrict__ out16, __half* Wl2, __half* Al,
                                          int t, long row0) {
    {   // stage Wt hi+lo: 2*128*136 halves = 4352 float4
        const float4* src = (const float4*)wt2;
        float4* dst = (float4*)Wl2;
        for (int i = t; i < 4352; i += 256) dst[i] = src[i];
    }
    __syncthreads();

    int w = t >> 6;            // wave 0..3 -> rows w*16..w*16+15
    int l = t & 63;
    int lr = l & 15;           // A row-in-tile / B col-in-tile / D col
    int lk = (l >> 4) * 8;     // k sub-block

    f32x4 acc[8];
#pragma unroll
    for (int i = 0; i < 8; ++i) acc[i] = (f32x4)(0.f);

#pragma unroll
    for (int ks = 0; ks < 4; ++ks) {
        f16x8 a = *(const f16x8*)&Al[(w * 16 + lr) * WTP + ks * 32 + lk];
#pragma unroll
        for (int tile = 0; tile < 8; ++tile) {
            f16x8 bh = *(const f16x8*)&Wl2[(tile * 16 + lr) * WTP + ks * 32 + lk];
            f16x8 bl = *(const f16x8*)&Wl2[DIM * WTP + (tile * 16 + lr) * WTP + ks * 32 + lk];
            acc[tile] = __builtin_amdgcn_mfma_f32_16x16x32_f16(a, bh, acc[tile], 0, 0, 0);
            acc[tile] = __builtin_amdgcn_mfma_f32_16x16x32_f16(a, bl, acc[tile], 0, 0, 0);
        }
    }

    long orow = row0 + w * 16 + (l >> 4) * 4;   // D: col=l&15, row=(l>>4)*4+i
#pragma unroll
    for (int tile = 0; tile < 8; ++tile) {
        int col = tile * 16 + lr;
        float b = bias[col];
#pragma unroll
        for (int i = 0; i < 4; ++i)
            out16[(orow + i) * DIM + col] = __float2half(acc[tile][i] + b);
    }
}

// layer 0: fp32 input, no affine
__global__ __launch_bounds__(256) void k_gemm_f32(const float* __restrict__ in, const __half* __restrict__ wt2,
                                                  const float* __restrict__ bias, __half* __restrict__ out16) {
    __shared__ __half Wl2[2 * DIM * WTP];
    __shared__ __half Al[64 * WTP];
    int t = threadIdx.x;
    long row0 = (long)blockIdx.x * 64;
    for (int i = t; i < 2048; i += 256) {   // 64 rows x 32 float4
        int r = i >> 5, k4 = i & 31;
        float4 v = ((const float4*)(in + (row0 + r) * DIM))[k4];
        __half2* d = (__half2*)&Al[r * WTP + k4 * 4];
        d[0] = __floats2half2_rn(v.x, v.y);
        d[1] = __floats2half2_rn(v.z, v.w);
    }
    gemm_core(wt2, bias, out16, Wl2, Al, t, row0);
}

// layers 1,2: fp16 input with BN affine
__global__ __launch_bounds__(256) void k_gemm_f16(const __half* __restrict__ in, const __half* __restrict__ wt2,
                                                  const float* __restrict__ bias, const float* __restrict__ ac,
                                                  __half* __restrict__ out16) {
    __shared__ __half Wl2[2 * DIM * WTP];
    __shared__ __half Al[64 * WTP];
    int t = threadIdx.x;
    long row0 = (long)blockIdx.x * 64;
    for (int i = t; i < 1024; i += 256) {   // 64 rows x 16 chunks of 8 halves
        int r = i >> 4, k8 = i & 15;
        const __half2* src = (const __half2*)(in + (row0 + r) * DIM + k8 * 8);
        int k = k8 * 8;
        float2 f0 = __half22float2(src[0]);
        float2 f1 = __half22float2(src[1]);
        float2 f2 = __half22float2(src[2]);
        float2 f3 = __half22float2(src[3]);
        f0.x = fmaf(ac[k + 0], f0.x, ac[DIM + k + 0]); f0.y = fmaf(ac[k + 1], f0.y, ac[DIM + k + 1]);
        f1.x = fmaf(ac[k + 2], f1.x, ac[DIM + k + 2]); f1.y = fmaf(ac[k + 3], f1.y, ac[DIM + k + 3]);
        f2.x = fmaf(ac[k + 4], f2.x, ac[DIM + k + 4]); f2.y = fmaf(ac[k + 5], f2.y, ac[DIM + k + 5]);
        f3.x = fmaf(ac[k + 6], f3.x, ac[DIM + k + 6]); f3.y = fmaf(ac[k + 7], f3.y, ac[DIM + k + 7]);
        __half2* d = (__half2*)&Al[r * WTP + k];
        d[0] = __floats2half2_rn(f0.x, f0.y);
        d[1] = __floats2half2_rn(f1.x, f1.y);
        d[2] = __floats2half2_rn(f2.x, f2.y);
        d[3] = __floats2half2_rn(f3.x, f3.y);
    }
    gemm_core(wt2, bias, out16, Wl2, Al, t, row0);
}

// ---------------- Aggregation + ReLU + BN partial stats -------------------
// elist is 4B src; coef = dinv[s]*di recomputed (dinv 160KB, L2-hot broadcast;
// issues in parallel with the row gather -- same dependent-chain depth).
__global__ __launch_bounds__(256) void k_agg(const __half* __restrict__ h16, const int* __restrict__ off,
                                             const int* __restrict__ elist,
                                             const float* __restrict__ dinv, __half* __restrict__ hout,
                                             float* __restrict__ partials) {
    __shared__ float colacc[256];
    colacc[threadIdx.x] = 0.f;
    __syncthreads();

    const __half2* rows = (const __half2*)h16;   // 64 half2 per row
    int lane = threadIdx.x & 63;
    int wid = (blockIdx.x * 256 + threadIdx.x) >> 6;
    const int NW = AGG_BLOCKS * 4;
    float s0 = 0.f, s1 = 0.f, q0 = 0.f, q1 = 0.f;

    for (int i = wid; i < N_NODES; i += NW) {
        float di = dinv[i];
        float selfc = di * di;
        float2 rv = __half22float2(rows[(long)i * 64 + lane]);
        float a0 = rv.x * selfc, a1 = rv.y * selfc;
        int e  = off[i];
        int e1 = off[i + 1];
#pragma unroll 4
        for (; e < e1; ++e) {
            int s = elist[e];
            float c = dinv[s] * di;
            float2 r = __half22float2(rows[(long)s * 64 + lane]);
            a0 = fmaf(r.x, c, a0);
            a1 = fmaf(r.y, c, a1);
        }
        a0 = fmaxf(a0, 0.f);
        a1 = fmaxf(a1, 0.f);
        ((__half2*)(hout + (long)i * DIM))[lane] = __floats2half2_rn(a0, a1);
        s0 += a0; q0 += a0 * a0; s1 += a1; q1 += a1 * a1;
    }

    // partials layout: [0..127] col sums, [128..255] col sumsq (true col idx)
    atomicAdd(&colacc[2 * lane],           s0);
    atomicAdd(&colacc[2 * lane + 1],       s1);
    atomicAdd(&colacc[128 + 2 * lane],     q0);
    atomicAdd(&colacc[128 + 2 * lane + 1], q1);
    __syncthreads();
    partials[(long)blockIdx.x * 256 + threadIdx.x] = colacc[threadIdx.x];
}

// ---------------- BN stats -> affine a,c (8 blocks x 16 cols) ----------------
__global__ __launch_bounds__(1024) void k_stats(const float* __restrict__ partials,
                                                const float* __restrict__ gamma, const float* __restrict__ beta,
                                                float* __restrict__ ac) {
    __shared__ float ls[1024], lq[1024];
    int dd = threadIdx.x & 15;
    int seg = threadIdx.x >> 4;                    // 64 segments
    int d = blockIdx.x * 16 + dd;
    float s = 0.f, q = 0.f;
    for (int b = seg; b < AGG_BLOCKS; b += 64) {
        s += partials[b * 256 + d];
        q += partials[b * 256 + 128 + d];
    }
    ls[threadIdx.x] = s; lq[threadIdx.x] = q;
    __syncthreads();
    for (int off = 512; off >= 16; off >>= 1) {
        if (threadIdx.x < off) {
            ls[threadIdx.x] += ls[threadIdx.x + off];
            lq[threadIdx.x] += lq[threadIdx.x + off];
        }
        __syncthreads();
    }
    if (threadIdx.x < 16) {
        s = ls[threadIdx.x]; q = lq[threadIdx.x];
        float mean = s * (1.f / N_NODES);
        float var  = q * (1.f / N_NODES) - mean * mean;
        float a = gamma[d] * rsqrtf(var + BN_EPS);
        ac[d] = a;
        ac[DIM + d] = fmaf(-mean, a, beta[d]);
    }
}

// ---------------- Pool (applies last BN affine); half2, 16 segments -------
__global__ __launch_bounds__(1024) void k_pool(const __half* __restrict__ h, const float* __restrict__ ac,
                                               const int* __restrict__ goff, float* __restrict__ pooled) {
    __shared__ float2 red[1024];
    int g = blockIdx.x;
    int d2 = threadIdx.x & 63;                     // col pair
    int seg = threadIdx.x >> 6;                    // 16 segments
    int r0 = goff[g], r1 = goff[g + 1];
    const __half2* rows = (const __half2*)h;
    float s0 = 0.f, s1 = 0.f;
    for (int r = r0 + seg; r < r1; r += 16) {
        float2 v = __half22float2(rows[(long)r * 64 + d2]);
        s0 += v.x; s1 += v.y;
    }
    red[threadIdx.x] = make_float2(s0, s1);
    __syncthreads();
    for (int off = 512; off >= 64; off >>= 1) {
        if (threadIdx.x < off) {
            red[threadIdx.x].x += red[threadIdx.x + off].x;
            red[threadIdx.x].y += red[threadIdx.x + off].y;
        }
        __syncthreads();
    }
    if (threadIdx.x < 64) {
        float2 s = red[threadIdx.x];
        int n = r1 - r0;
        float fn = (float)n;
        float denom = (float)(n > 0 ? n : 1);
        int d = 2 * threadIdx.x;
        pooled[g * DIM + d]     = (ac[d] * s.x     + ac[DIM + d] * fn)     / denom;
        pooled[g * DIM + d + 1] = (ac[d + 1] * s.y + ac[DIM + d + 1] * fn) / denom;
    }
}

// ---------------- Final MLP ----------------
__global__ __launch_bounds__(64) void k_mlp(const float* __restrict__ pooled, const float* __restrict__ w1,
                                            const float* __restrict__ b1, const float* __restrict__ w2,
                                            const float* __restrict__ b2, float* __restrict__ out) {
    int g = blockIdx.x, j = threadIdx.x;
    const float* p = pooled + g * DIM;
    float h = b1[j];
#pragma unroll
    for (int k = 0; k < DIM; ++k) h = fmaf(p[k], w1[k * 64 + j], h);
    h = fmaxf(h, 0.f);
    float v = h * w2[j];
#pragma unroll
    for (int o = 32; o > 0; o >>= 1) v += __shfl_down(v, o);
    if (j == 0) out[g] = v + b2[0];
}

extern "C" void kernel_launch(void* const* d_in, const int* in_sizes, int n_in,
                              void* d_out, int out_size, void* d_ws, size_t ws_size,
                              hipStream_t stream) {
    const float* x      = (const float*)d_in[0];
    const int*   ei     = (const int*)d_in[1];
    const int*   batch  = (const int*)d_in[2];
    const float* Ws     = (const float*)d_in[3];
    const float* bs     = (const float*)d_in[4];
    const float* gammas = (const float*)d_in[5];
    const float* betas  = (const float*)d_in[6];
    const float* w1     = (const float*)d_in[7];
    const float* b1     = (const float*)d_in[8];
    const float* w2     = (const float*)d_in[9];
    const float* b2     = (const float*)d_in[10];
    float* out = (float*)d_out;

    char* p = (char*)d_ws;
    auto alloc = [&](size_t bytes) { void* r = (void*)p; p += (bytes + 255) & ~(size_t)255; return r; };
    int*    cnt      = (int*)alloc((size_t)N_NODES * 4);
    int*    off      = (int*)alloc((size_t)(N_NODES + 1) * 4);
    int*    rank     = (int*)alloc((size_t)N_EDGES * 4);
    int*    goff     = (int*)alloc((size_t)(N_GRAPHS + 1) * 4);
    int*    blocksum = (int*)alloc((size_t)(SCAN_NB + 1) * 4);
    int*    elist    = (int*)alloc((size_t)N_EDGES * 4);
    float*  dinv     = (float*)alloc((size_t)N_NODES * 4);
    __half* wt       = (__half*)alloc((size_t)3 * 2 * DIM * WTP * 2);
    __half* h16      = (__half*)alloc((size_t)N_NODES * DIM * 2);
    __half* v16      = (__half*)alloc((size_t)N_NODES * DIM * 2);
    float*  parts    = (float*)alloc((size_t)AGG_BLOCKS * 256 * 4);
    float*  ac       = (float*)alloc(256 * 4);
    float*  pooled   = (float*)alloc((size_t)N_GRAPHS * DIM * 4);

    hipMemsetAsync(cnt, 0, (size_t)N_NODES * 4, stream);

    k_count_edges<<<(N_EDGES + 255) / 256, 256, 0, stream>>>(ei, cnt, rank);
    k_scan_blk<<<SCAN_NB, 1024, 0, stream>>>(cnt, off, blocksum);
    k_scan_fix<<<SCAN_NB, 1024, 0, stream>>>(cnt, blocksum, off, dinv, batch, goff);
    k_fill<<<(N_EDGES + 255) / 256, 256, 0, stream>>>(ei, rank, off, elist);
    k_prepw<<<(3 * DIM * DIM + 255) / 256, 256, 0, stream>>>(Ws, wt);

    for (int l = 0; l < 3; ++l) {
        if (l == 0)
            k_gemm_f32<<<GEMM_NB, 256, 0, stream>>>(x, wt, bs, h16);
        else
            k_gemm_f16<<<GEMM_NB, 256, 0, stream>>>(v16, wt + (size_t)l * 2 * DIM * WTP,
                                                    bs + (size_t)l * DIM, ac, h16);
        k_agg<<<AGG_BLOCKS, 256, 0, stream>>>(h16, off, elist, dinv, v16, parts);
        k_stats<<<8, 1024, 0, stream>>>(parts, gammas + (size_t)l * DIM, betas + (size_t)l * DIM, ac);
    }
    k_pool<<<N_GRAPHS, 1024, 0, stream>>>(v16, ac, goff, pooled);
    k_mlp<<<N_GRAPHS, 64, 0, stream>>>(pooled, w1, b1, w2, b2, out);
}

// Round 15
// 260.410 us; speedup vs baseline: 1.6781x; 1.0608x over previous
//
#include <hip/hip_runtime.h>
#include <hip/hip_fp16.h>

#define N_NODES 40000
#define N_EDGES 640000
#define DIM 128
#define N_GRAPHS 64
#define BN_EPS 1e-5f
#define AGG_BLOCKS 2048
#define SCAN_NB 40   // ceil(40000/1024)
#define NTILES 625   // 64-row tiles
#define GEMM_BLOCKS 256
#define WTP 136      // padded k-stride for Wt / A tiles (halves)

typedef _Float16 f16x8 __attribute__((ext_vector_type(8)));
typedef float    f32x4 __attribute__((ext_vector_type(4)));

// ---------------- CSR build ----------------
__global__ __launch_bounds__(256) void k_count_edges(const int* __restrict__ ei, int* __restrict__ cnt,
                                                     int* __restrict__ rank) {
    int e = blockIdx.x * 256 + threadIdx.x;
    if (e < N_EDGES) rank[e] = atomicAdd(&cnt[ei[N_EDGES + e]], 1);
}

__global__ __launch_bounds__(1024) void k_scan_blk(const int* __restrict__ cnt, int* __restrict__ off,
                                                   int* __restrict__ blocksum) {
    __shared__ int sums[1024];
    int i = blockIdx.x * 1024 + threadIdx.x;
    int v = (i < N_NODES) ? cnt[i] : 0;
    sums[threadIdx.x] = v;
    __syncthreads();
    for (int d = 1; d < 1024; d <<= 1) {
        int t = (threadIdx.x >= d) ? sums[threadIdx.x - d] : 0;
        __syncthreads();
        sums[threadIdx.x] += t;
        __syncthreads();
    }
    if (i < N_NODES) off[i] = sums[threadIdx.x] - v;        // exclusive within block
    if (threadIdx.x == 1023) blocksum[blockIdx.x] = sums[1023];
}

__global__ __launch_bounds__(1024) void k_scan_fix(const int* __restrict__ cnt, const int* __restrict__ blocksum,
                                                   int* __restrict__ off, float* __restrict__ dinv,
                                                   const int* __restrict__ batch, int* __restrict__ goff) {
    __shared__ int bo[2];
    if (threadIdx.x == 0) {
        int run = 0, tot = 0;
        for (int b = 0; b < SCAN_NB; ++b) {
            int v = blocksum[b];
            if (b < (int)blockIdx.x) run += v;
            tot += v;
        }
        bo[0] = run; bo[1] = tot;
    }
    __syncthreads();
    int i = blockIdx.x * 1024 + threadIdx.x;
    if (i < N_NODES) {
        off[i] += bo[0];
        dinv[i] = rsqrtf((float)(cnt[i] + 1));              // +1 self loop, always > 0
        int b = batch[i];
        int bp = (i == 0) ? -1 : batch[i - 1];
        for (int g = bp + 1; g <= b; ++g) goff[g] = i;      // rare divergence
        if (i == N_NODES - 1)
            for (int g = b + 1; g <= N_GRAPHS; ++g) goff[g] = N_NODES;
    }
    if (i == 0) off[N_NODES] = bo[1];
}

// no atomic: slot = off[dst] + rank[e]; scatter 4B src index only
__global__ __launch_bounds__(256) void k_fill(const int* __restrict__ ei, const int* __restrict__ rank,
                                              const int* __restrict__ off, int* __restrict__ elist) {
    int e = blockIdx.x * 256 + threadIdx.x;
    if (e < N_EDGES) {
        int s = ei[e];                 // src row
        int d = ei[N_EDGES + e];       // dst row
        elist[off[d] + rank[e]] = s;
    }
}

// ---- W prep: per layer, transposed hi/lo fp16 split, padded [c][WTP] ----
__global__ __launch_bounds__(256) void k_prepw(const float* __restrict__ Ws, __half* __restrict__ wt) {
    int idx = blockIdx.x * 256 + threadIdx.x;        // 3*128*128
    if (idx >= 3 * DIM * DIM) return;
    int l = idx >> 14;
    int rem = idx & 16383;
    int k = rem >> 7;         // row of W
    int c = rem & 127;        // col of W
    float w = Ws[(size_t)l * DIM * DIM + k * DIM + c];
    __half hi = __float2half(w);
    __half lo = __float2half(w - __half2float(hi));
    size_t base = (size_t)l * 2 * DIM * WTP;
    wt[base + (size_t)c * WTP + k] = hi;
    wt[base + (size_t)DIM * WTP + (size_t)c * WTP + k] = lo;
}

// ---------------- GEMM building blocks ----------------
__device__ __forceinline__ void stage_a_f32(const float* __restrict__ in, __half* Al, long row0, int t) {
    for (int i = t; i < 2048; i += 256) {   // 64 rows x 32 float4
        int r = i >> 5, k4 = i & 31;
        float4 v = ((const float4*)(in + (row0 + r) * DIM))[k4];
        __half2* d = (__half2*)&Al[r * WTP + k4 * 4];
        d[0] = __floats2half2_rn(v.x, v.y);
        d[1] = __floats2half2_rn(v.z, v.w);
    }
}

__device__ __forceinline__ void stage_a_f16(const __half* __restrict__ in, const float* __restrict__ ac,
                                            __half* Al, long row0, int t) {
    for (int i = t; i < 1024; i += 256) {   // 64 rows x 16 chunks of 8 halves
        int r = i >> 4, k8 = i & 15;
        const __half2* src = (const __half2*)(in + (row0 + r) * DIM + k8 * 8);
        int k = k8 * 8;
        float2 f0 = __half22float2(src[0]);
        float2 f1 = __half22float2(src[1]);
        float2 f2 = __half22float2(src[2]);
        float2 f3 = __half22float2(src[3]);
        f0.x = fmaf(ac[k + 0], f0.x, ac[DIM + k + 0]); f0.y = fmaf(ac[k + 1], f0.y, ac[DIM + k + 1]);
        f1.x = fmaf(ac[k + 2], f1.x, ac[DIM + k + 2]); f1.y = fmaf(ac[k + 3], f1.y, ac[DIM + k + 3]);
        f2.x = fmaf(ac[k + 4], f2.x, ac[DIM + k + 4]); f2.y = fmaf(ac[k + 5], f2.y, ac[DIM + k + 5]);
        f3.x = fmaf(ac[k + 6], f3.x, ac[DIM + k + 6]); f3.y = fmaf(ac[k + 7], f3.y, ac[DIM + k + 7]);
        __half2* d = (__half2*)&Al[r * WTP + k];
        d[0] = __floats2half2_rn(f0.x, f0.y);
        d[1] = __floats2half2_rn(f1.x, f1.y);
        d[2] = __floats2half2_rn(f2.x, f2.y);
        d[3] = __floats2half2_rn(f3.x, f3.y);
    }
}

__device__ __forceinline__ void compute_tile(const __half* Wl2, const __half* Al,
                                             const float* __restrict__ bias, __half* __restrict__ out16,
                                             int t, long row0) {
    int w = t >> 6;            // wave 0..3 -> rows w*16..w*16+15
    int l = t & 63;
    int lr = l & 15;           // A row-in-tile / B col-in-tile / D col
    int lk = (l >> 4) * 8;     // k sub-block

    f32x4 acc[8];
#pragma unroll
    for (int i = 0; i < 8; ++i) acc[i] = (f32x4)(0.f);

#pragma unroll
    for (int ks = 0; ks < 4; ++ks) {
        f16x8 a = *(const f16x8*)&Al[(w * 16 + lr) * WTP + ks * 32 + lk];
#pragma unroll
        for (int tile = 0; tile < 8; ++tile) {
            f16x8 bh = *(const f16x8*)&Wl2[(tile * 16 + lr) * WTP + ks * 32 + lk];
            f16x8 bl = *(const f16x8*)&Wl2[DIM * WTP + (tile * 16 + lr) * WTP + ks * 32 + lk];
            acc[tile] = __builtin_amdgcn_mfma_f32_16x16x32_f16(a, bh, acc[tile], 0, 0, 0);
            acc[tile] = __builtin_amdgcn_mfma_f32_16x16x32_f16(a, bl, acc[tile], 0, 0, 0);
        }
    }

    long orow = row0 + w * 16 + (l >> 4) * 4;   // D: col=l&15, row=(l>>4)*4+i
#pragma unroll
    for (int tile = 0; tile < 8; ++tile) {
        int col = tile * 16 + lr;
        float b = bias[col];
#pragma unroll
        for (int i = 0; i < 4; ++i)
            out16[(orow + i) * DIM + col] = __float2half(acc[tile][i] + b);
    }
}

// persistent-block GEMM: W staged once/block; A-tile double-buffered.
__global__ __launch_bounds__(256) void k_gemm_f32(const float* __restrict__ in, const __half* __restrict__ wt2,
                                                  const float* __restrict__ bias, __half* __restrict__ out16) {
    __shared__ __half Wl2[2 * DIM * WTP];
    __shared__ __half Al[2][64 * WTP];
    int t = threadIdx.x;
    {
        const float4* src = (const float4*)wt2;
        float4* dst = (float4*)Wl2;
        for (int i = t; i < 4352; i += 256) dst[i] = src[i];
    }
    int tile = blockIdx.x;
    stage_a_f32(in, Al[0], (long)tile * 64, t);
    __syncthreads();
    int buf = 0;
    while (tile < NTILES) {
        int next = tile + GEMM_BLOCKS;
        if (next < NTILES) stage_a_f32(in, Al[buf ^ 1], (long)next * 64, t);
        compute_tile(Wl2, Al[buf], bias, out16, t, (long)tile * 64);
        __syncthreads();
        buf ^= 1;
        tile = next;
    }
}

__global__ __launch_bounds__(256) void k_gemm_f16(const __half* __restrict__ in, const __half* __restrict__ wt2,
                                                  const float* __restrict__ bias, const float* __restrict__ ac,
                                                  __half* __restrict__ out16) {
    __shared__ __half Wl2[2 * DIM * WTP];
    __shared__ __half Al[2][64 * WTP];
    int t = threadIdx.x;
    {
        const float4* src = (const float4*)wt2;
        float4* dst = (float4*)Wl2;
        for (int i = t; i < 4352; i += 256) dst[i] = src[i];
    }
    int tile = blockIdx.x;
    stage_a_f16(in, ac, Al[0], (long)tile * 64, t);
    __syncthreads();
    int buf = 0;
    while (tile < NTILES) {
        int next = tile + GEMM_BLOCKS;
        if (next < NTILES) stage_a_f16(in, ac, Al[buf ^ 1], (long)next * 64, t);
        compute_tile(Wl2, Al[buf], bias, out16, t, (long)tile * 64);
        __syncthreads();
        buf ^= 1;
        tile = next;
    }
}

// ---------------- Aggregation + ReLU + BN partial stats -------------------
__global__ __launch_bounds__(256) void k_agg(const __half* __restrict__ h16, const int* __restrict__ off,
                                             const int* __restrict__ elist,
                                             const float* __restrict__ dinv, __half* __restrict__ hout,
                                             float* __restrict__ partials) {
    __shared__ float colacc[256];
    colacc[threadIdx.x] = 0.f;
    __syncthreads();

    const __half2* rows = (const __half2*)h16;   // 64 half2 per row
    int lane = threadIdx.x & 63;
    int wid = (blockIdx.x * 256 + threadIdx.x) >> 6;
    const int NW = AGG_BLOCKS * 4;
    float s0 = 0.f, s1 = 0.f, q0 = 0.f, q1 = 0.f;

    for (int i = wid; i < N_NODES; i += NW) {
        float di = dinv[i];
        float selfc = di * di;
        float2 rv = __half22float2(rows[(long)i * 64 + lane]);
        float a0 = rv.x * selfc, a1 = rv.y * selfc;
        int e  = off[i];
        int e1 = off[i + 1];
#pragma unroll 4
        for (; e < e1; ++e) {
            int s = elist[e];
            float c = dinv[s] * di;
            float2 r = __half22float2(rows[(long)s * 64 + lane]);
            a0 = fmaf(r.x, c, a0);
            a1 = fmaf(r.y, c, a1);
        }
        a0 = fmaxf(a0, 0.f);
        a1 = fmaxf(a1, 0.f);
        ((__half2*)(hout + (long)i * DIM))[lane] = __floats2half2_rn(a0, a1);
        s0 += a0; q0 += a0 * a0; s1 += a1; q1 += a1 * a1;
    }

    atomicAdd(&colacc[2 * lane],           s0);
    atomicAdd(&colacc[2 * lane + 1],       s1);
    atomicAdd(&colacc[128 + 2 * lane],     q0);
    atomicAdd(&colacc[128 + 2 * lane + 1], q1);
    __syncthreads();
    partials[(long)blockIdx.x * 256 + threadIdx.x] = colacc[threadIdx.x];
}

// ---------------- BN stats -> affine a,c (8 blocks x 16 cols) ----------------
__global__ __launch_bounds__(1024) void k_stats(const float* __restrict__ partials,
                                                const float* __restrict__ gamma, const float* __restrict__ beta,
                                                float* __restrict__ ac) {
    __shared__ float ls[1024], lq[1024];
    int dd = threadIdx.x & 15;
    int seg = threadIdx.x >> 4;                    // 64 segments
    int d = blockIdx.x * 16 + dd;
    float s = 0.f, q = 0.f;
    for (int b = seg; b < AGG_BLOCKS; b += 64) {
        s += partials[b * 256 + d];
        q += partials[b * 256 + 128 + d];
    }
    ls[threadIdx.x] = s; lq[threadIdx.x] = q;
    __syncthreads();
    for (int off = 512; off >= 16; off >>= 1) {
        if (threadIdx.x < off) {
            ls[threadIdx.x] += ls[threadIdx.x + off];
            lq[threadIdx.x] += lq[threadIdx.x + off];
        }
        __syncthreads();
    }
    if (threadIdx.x < 16) {
        s = ls[threadIdx.x]; q = lq[threadIdx.x];
        float mean = s * (1.f / N_NODES);
        float var  = q * (1.f / N_NODES) - mean * mean;
        float a = gamma[d] * rsqrtf(var + BN_EPS);
        ac[d] = a;
        ac[DIM + d] = fmaf(-mean, a, beta[d]);
    }
}

// ---------------- Pool + final MLP fused (per graph) ----------------
__global__ __launch_bounds__(1024) void k_poolmlp(const __half* __restrict__ h, const float* __restrict__ ac,
                                                  const int* __restrict__ goff,
                                                  const float* __restrict__ w1, const float* __restrict__ b1,
                                                  const float* __restrict__ w2, const float* __restrict__ b2,
                                                  float* __restrict__ out) {
    __shared__ float2 red[1024];
    __shared__ float pl[DIM];
    int g = blockIdx.x;
    int d2 = threadIdx.x & 63;                     // col pair
    int seg = threadIdx.x >> 6;                    // 16 segments
    int r0 = goff[g], r1 = goff[g + 1];
    const __half2* rows = (const __half2*)h;
    float s0 = 0.f, s1 = 0.f;
    for (int r = r0 + seg; r < r1; r += 16) {
        float2 v = __half22float2(rows[(long)r * 64 + d2]);
        s0 += v.x; s1 += v.y;
    }
    red[threadIdx.x] = make_float2(s0, s1);
    __syncthreads();
    for (int off = 512; off >= 64; off >>= 1) {
        if (threadIdx.x < off) {
            red[threadIdx.x].x += red[threadIdx.x + off].x;
            red[threadIdx.x].y += red[threadIdx.x + off].y;
        }
        __syncthreads();
    }
    if (threadIdx.x < 64) {
        float2 s = red[threadIdx.x];
        int n = r1 - r0;
        float fn = (float)n;
        float denom = (float)(n > 0 ? n : 1);
        int d = 2 * threadIdx.x;
        pl[d]     = (ac[d] * s.x     + ac[DIM + d] * fn)     / denom;
        pl[d + 1] = (ac[d + 1] * s.y + ac[DIM + d + 1] * fn) / denom;
    }
    __syncthreads();
    if (threadIdx.x < 64) {
        int j = threadIdx.x;
        float hh = b1[j];
#pragma unroll
        for (int k = 0; k < DIM; ++k) hh = fmaf(pl[k], w1[k * 64 + j], hh);
        hh = fmaxf(hh, 0.f);
        float v = hh * w2[j];
#pragma unroll
        for (int o = 32; o > 0; o >>= 1) v += __shfl_down(v, o);
        if (j == 0) out[g] = v + b2[0];
    }
}

extern "C" void kernel_launch(void* const* d_in, const int* in_sizes, int n_in,
                              void* d_out, int out_size, void* d_ws, size_t ws_size,
                              hipStream_t stream) {
    const float* x      = (const float*)d_in[0];
    const int*   ei     = (const int*)d_in[1];
    const int*   batch  = (const int*)d_in[2];
    const float* Ws     = (const float*)d_in[3];
    const float* bs     = (const float*)d_in[4];
    const float* gammas = (const float*)d_in[5];
    const float* betas  = (const float*)d_in[6];
    const float* w1     = (const float*)d_in[7];
    const float* b1     = (const float*)d_in[8];
    const float* w2     = (const float*)d_in[9];
    const float* b2     = (const float*)d_in[10];
    float* out = (float*)d_out;

    char* p = (char*)d_ws;
    auto alloc = [&](size_t bytes) { void* r = (void*)p; p += (bytes + 255) & ~(size_t)255; return r; };
    int*    cnt      = (int*)alloc((size_t)N_NODES * 4);
    int*    off      = (int*)alloc((size_t)(N_NODES + 1) * 4);
    int*    rank     = (int*)alloc((size_t)N_EDGES * 4);
    int*    goff     = (int*)alloc((size_t)(N_GRAPHS + 1) * 4);
    int*    blocksum = (int*)alloc((size_t)(SCAN_NB + 1) * 4);
    int*    elist    = (int*)alloc((size_t)N_EDGES * 4);
    float*  dinv     = (float*)alloc((size_t)N_NODES * 4);
    __half* wt       = (__half*)alloc((size_t)3 * 2 * DIM * WTP * 2);
    __half* h16      = (__half*)alloc((size_t)N_NODES * DIM * 2);
    __half* v16      = (__half*)alloc((size_t)N_NODES * DIM * 2);
    float*  parts    = (float*)alloc((size_t)AGG_BLOCKS * 256 * 4);
    float*  ac       = (float*)alloc(256 * 4);

    hipMemsetAsync(cnt, 0, (size_t)N_NODES * 4, stream);

    k_count_edges<<<(N_EDGES + 255) / 256, 256, 0, stream>>>(ei, cnt, rank);
    k_scan_blk<<<SCAN_NB, 1024, 0, stream>>>(cnt, off, blocksum);
    k_scan_fix<<<SCAN_NB, 1024, 0, stream>>>(cnt, blocksum, off, dinv, batch, goff);
    k_fill<<<(N_EDGES + 255) / 256, 256, 0, stream>>>(ei, rank, off, elist);
    k_prepw<<<(3 * DIM * DIM + 255) / 256, 256, 0, stream>>>(Ws, wt);

    for (int l = 0; l < 3; ++l) {
        if (l == 0)
            k_gemm_f32<<<GEMM_BLOCKS, 256, 0, stream>>>(x, wt, bs, h16);
        else
            k_gemm_f16<<<GEMM_BLOCKS, 256, 0, stream>>>(v16, wt + (size_t)l * 2 * DIM * WTP,
                                                        bs + (size_t)l * DIM, ac, h16);
        k_agg<<<AGG_BLOCKS, 256, 0, stream>>>(h16, off, elist, dinv, v16, parts);
        k_stats<<<8, 1024, 0, stream>>>(parts, gammas + (size_t)l * DIM, betas + (size_t)l * DIM, ac);
    }
    k_poolmlp<<<N_GRAPHS, 1024, 0, stream>>>(v16, ac, goff, w1, b1, w2, b2, out);
}

// Round 16
// 238.373 us; speedup vs baseline: 1.8332x; 1.0924x over previous
//
#include <hip/hip_runtime.h>
#include <hip/hip_fp16.h>

#define N_NODES 40000
#define N_EDGES 640000
#define DIM 128
#define N_GRAPHS 64
#define BN_EPS 1e-5f
#define AGG_BLOCKS 512           // x 1024 threads = 8192 waves (same as before)
#define SCAN_NB 40   // ceil(40000/1024)
#define NTILES 625   // 64-row tiles
#define GEMM_BLOCKS 256
#define WTP 136      // padded k-stride for Wt / A tiles (halves)
#define FILL_NB ((N_EDGES + 255) / 256)           // 2500
#define PREPW_NB ((3 * DIM * DIM + 255) / 256)    // 192

typedef _Float16 f16x8 __attribute__((ext_vector_type(8)));
typedef float    f32x4 __attribute__((ext_vector_type(4)));

// ---------------- CSR build ----------------
__global__ __launch_bounds__(256) void k_count_edges(const int* __restrict__ ei, int* __restrict__ cnt,
                                                     int* __restrict__ rank) {
    int e = blockIdx.x * 256 + threadIdx.x;
    if (e < N_EDGES) rank[e] = atomicAdd(&cnt[ei[N_EDGES + e]], 1);
}

__global__ __launch_bounds__(1024) void k_scan_blk(const int* __restrict__ cnt, int* __restrict__ off,
                                                   int* __restrict__ blocksum) {
    __shared__ int sums[1024];
    int i = blockIdx.x * 1024 + threadIdx.x;
    int v = (i < N_NODES) ? cnt[i] : 0;
    sums[threadIdx.x] = v;
    __syncthreads();
    for (int d = 1; d < 1024; d <<= 1) {
        int t = (threadIdx.x >= d) ? sums[threadIdx.x - d] : 0;
        __syncthreads();
        sums[threadIdx.x] += t;
        __syncthreads();
    }
    if (i < N_NODES) off[i] = sums[threadIdx.x] - v;        // exclusive within block
    if (threadIdx.x == 1023) blocksum[blockIdx.x] = sums[1023];
}

__global__ __launch_bounds__(1024) void k_scan_fix(const int* __restrict__ cnt, const int* __restrict__ blocksum,
                                                   int* __restrict__ off, float* __restrict__ dinv,
                                                   const int* __restrict__ batch, int* __restrict__ goff) {
    __shared__ int bo[2];
    if (threadIdx.x == 0) {
        int run = 0, tot = 0;
        for (int b = 0; b < SCAN_NB; ++b) {
            int v = blocksum[b];
            if (b < (int)blockIdx.x) run += v;
            tot += v;
        }
        bo[0] = run; bo[1] = tot;
    }
    __syncthreads();
    int i = blockIdx.x * 1024 + threadIdx.x;
    if (i < N_NODES) {
        off[i] += bo[0];
        dinv[i] = rsqrtf((float)(cnt[i] + 1));              // +1 self loop, always > 0
        int b = batch[i];
        int bp = (i == 0) ? -1 : batch[i - 1];
        for (int g = bp + 1; g <= b; ++g) goff[g] = i;      // rare divergence
        if (i == N_NODES - 1)
            for (int g = b + 1; g <= N_GRAPHS; ++g) goff[g] = N_NODES;
    }
    if (i == 0) off[N_NODES] = bo[1];
}

// fill (blocks < FILL_NB) + W prep (blocks >= FILL_NB) merged in one dispatch
__global__ __launch_bounds__(256) void k_fill_prepw(const int* __restrict__ ei, const int* __restrict__ rank,
                                                    const int* __restrict__ off, int* __restrict__ elist,
                                                    const float* __restrict__ Ws, __half* __restrict__ wt) {
    if (blockIdx.x < FILL_NB) {
        int e = blockIdx.x * 256 + threadIdx.x;
        if (e < N_EDGES) {
            int s = ei[e];                 // src row
            int d = ei[N_EDGES + e];       // dst row
            elist[off[d] + rank[e]] = s;   // 4B scatter; coef recomputed in agg
        }
    } else {
        int idx = (blockIdx.x - FILL_NB) * 256 + threadIdx.x;   // 3*128*128
        if (idx < 3 * DIM * DIM) {
            int l = idx >> 14;
            int rem = idx & 16383;
            int k = rem >> 7;         // row of W
            int c = rem & 127;        // col of W
            float w = Ws[(size_t)l * DIM * DIM + k * DIM + c];
            __half hi = __float2half(w);
            __half lo = __float2half(w - __half2float(hi));
            size_t base = (size_t)l * 2 * DIM * WTP;
            wt[base + (size_t)c * WTP + k] = hi;
            wt[base + (size_t)DIM * WTP + (size_t)c * WTP + k] = lo;
        }
    }
}

// ---------------- GEMM building blocks ----------------
__device__ __forceinline__ void stage_a_f32(const float* __restrict__ in, __half* Al, long row0, int t) {
    for (int i = t; i < 2048; i += 256) {   // 64 rows x 32 float4
        int r = i >> 5, k4 = i & 31;
        float4 v = ((const float4*)(in + (row0 + r) * DIM))[k4];
        __half2* d = (__half2*)&Al[r * WTP + k4 * 4];
        d[0] = __floats2half2_rn(v.x, v.y);
        d[1] = __floats2half2_rn(v.z, v.w);
    }
}

__device__ __forceinline__ void stage_a_f16(const __half* __restrict__ in, const float* __restrict__ ac,
                                            __half* Al, long row0, int t) {
    for (int i = t; i < 1024; i += 256) {   // 64 rows x 16 chunks of 8 halves
        int r = i >> 4, k8 = i & 15;
        const __half2* src = (const __half2*)(in + (row0 + r) * DIM + k8 * 8);
        int k = k8 * 8;
        float2 f0 = __half22float2(src[0]);
        float2 f1 = __half22float2(src[1]);
        float2 f2 = __half22float2(src[2]);
        float2 f3 = __half22float2(src[3]);
        f0.x = fmaf(ac[k + 0], f0.x, ac[DIM + k + 0]); f0.y = fmaf(ac[k + 1], f0.y, ac[DIM + k + 1]);
        f1.x = fmaf(ac[k + 2], f1.x, ac[DIM + k + 2]); f1.y = fmaf(ac[k + 3], f1.y, ac[DIM + k + 3]);
        f2.x = fmaf(ac[k + 4], f2.x, ac[DIM + k + 4]); f2.y = fmaf(ac[k + 5], f2.y, ac[DIM + k + 5]);
        f3.x = fmaf(ac[k + 6], f3.x, ac[DIM + k + 6]); f3.y = fmaf(ac[k + 7], f3.y, ac[DIM + k + 7]);
        __half2* d = (__half2*)&Al[r * WTP + k];
        d[0] = __floats2half2_rn(f0.x, f0.y);
        d[1] = __floats2half2_rn(f1.x, f1.y);
        d[2] = __floats2half2_rn(f2.x, f2.y);
        d[3] = __floats2half2_rn(f3.x, f3.y);
    }
}

__device__ __forceinline__ void compute_tile(const __half* Wl2, const __half* Al,
                                             const float* __restrict__ bias, __half* __restrict__ out16,
                                             int t, long row0) {
    int w = t >> 6;            // wave 0..3 -> rows w*16..w*16+15
    int l = t & 63;
    int lr = l & 15;           // A row-in-tile / B col-in-tile / D col
    int lk = (l >> 4) * 8;     // k sub-block

    f32x4 acc[8];
#pragma unroll
    for (int i = 0; i < 8; ++i) acc[i] = (f32x4)(0.f);

#pragma unroll
    for (int ks = 0; ks < 4; ++ks) {
        f16x8 a = *(const f16x8*)&Al[(w * 16 + lr) * WTP + ks * 32 + lk];
#pragma unroll
        for (int tile = 0; tile < 8; ++tile) {
            f16x8 bh = *(const f16x8*)&Wl2[(tile * 16 + lr) * WTP + ks * 32 + lk];
            f16x8 bl = *(const f16x8*)&Wl2[DIM * WTP + (tile * 16 + lr) * WTP + ks * 32 + lk];
            acc[tile] = __builtin_amdgcn_mfma_f32_16x16x32_f16(a, bh, acc[tile], 0, 0, 0);
            acc[tile] = __builtin_amdgcn_mfma_f32_16x16x32_f16(a, bl, acc[tile], 0, 0, 0);
        }
    }

    long orow = row0 + w * 16 + (l >> 4) * 4;   // D: col=l&15, row=(l>>4)*4+i
#pragma unroll
    for (int tile = 0; tile < 8; ++tile) {
        int col = tile * 16 + lr;
        float b = bias[col];
#pragma unroll
        for (int i = 0; i < 4; ++i)
            out16[(orow + i) * DIM + col] = __float2half(acc[tile][i] + b);
    }
}

// persistent-block GEMM: W staged once/block; A-tile double-buffered.
__global__ __launch_bounds__(256) void k_gemm_f32(const float* __restrict__ in, const __half* __restrict__ wt2,
                                                  const float* __restrict__ bias, __half* __restrict__ out16) {
    __shared__ __half Wl2[2 * DIM * WTP];
    __shared__ __half Al[2][64 * WTP];
    int t = threadIdx.x;
    {
        const float4* src = (const float4*)wt2;
        float4* dst = (float4*)Wl2;
        for (int i = t; i < 4352; i += 256) dst[i] = src[i];
    }
    int tile = blockIdx.x;
    stage_a_f32(in, Al[0], (long)tile * 64, t);
    __syncthreads();
    int buf = 0;
    while (tile < NTILES) {
        int next = tile + GEMM_BLOCKS;
        if (next < NTILES) stage_a_f32(in, Al[buf ^ 1], (long)next * 64, t);
        compute_tile(Wl2, Al[buf], bias, out16, t, (long)tile * 64);
        __syncthreads();
        buf ^= 1;
        tile = next;
    }
}

__global__ __launch_bounds__(256) void k_gemm_f16(const __half* __restrict__ in, const __half* __restrict__ wt2,
                                                  const float* __restrict__ bias, const float* __restrict__ ac,
                                                  __half* __restrict__ out16) {
    __shared__ __half Wl2[2 * DIM * WTP];
    __shared__ __half Al[2][64 * WTP];
    int t = threadIdx.x;
    {
        const float4* src = (const float4*)wt2;
        float4* dst = (float4*)Wl2;
        for (int i = t; i < 4352; i += 256) dst[i] = src[i];
    }
    int tile = blockIdx.x;
    stage_a_f16(in, ac, Al[0], (long)tile * 64, t);
    __syncthreads();
    int buf = 0;
    while (tile < NTILES) {
        int next = tile + GEMM_BLOCKS;
        if (next < NTILES) stage_a_f16(in, ac, Al[buf ^ 1], (long)next * 64, t);
        compute_tile(Wl2, Al[buf], bias, out16, t, (long)tile * 64);
        __syncthreads();
        buf ^= 1;
        tile = next;
    }
}

// ---------------- Aggregation + ReLU + BN partial stats -------------------
// 512 blocks x 1024 threads (16 waves) = same 8192 waves / node mapping.
__global__ __launch_bounds__(1024) void k_agg(const __half* __restrict__ h16, const int* __restrict__ off,
                                              const int* __restrict__ elist,
                                              const float* __restrict__ dinv, __half* __restrict__ hout,
                                              float* __restrict__ partials) {
    __shared__ float colacc[256];
    if (threadIdx.x < 256) colacc[threadIdx.x] = 0.f;
    __syncthreads();

    const __half2* rows = (const __half2*)h16;   // 64 half2 per row
    int lane = threadIdx.x & 63;
    int wid = (blockIdx.x * 1024 + threadIdx.x) >> 6;
    const int NW = AGG_BLOCKS * 16;
    float s0 = 0.f, s1 = 0.f, q0 = 0.f, q1 = 0.f;

    for (int i = wid; i < N_NODES; i += NW) {
        float di = dinv[i];
        float selfc = di * di;
        float2 rv = __half22float2(rows[(long)i * 64 + lane]);
        float a0 = rv.x * selfc, a1 = rv.y * selfc;
        int e  = off[i];
        int e1 = off[i + 1];
#pragma unroll 4
        for (; e < e1; ++e) {
            int s = elist[e];
            float c = dinv[s] * di;
            float2 r = __half22float2(rows[(long)s * 64 + lane]);
            a0 = fmaf(r.x, c, a0);
            a1 = fmaf(r.y, c, a1);
        }
        a0 = fmaxf(a0, 0.f);
        a1 = fmaxf(a1, 0.f);
        ((__half2*)(hout + (long)i * DIM))[lane] = __floats2half2_rn(a0, a1);
        s0 += a0; q0 += a0 * a0; s1 += a1; q1 += a1 * a1;
    }

    // partials layout: [0..127] col sums, [128..255] col sumsq (true col idx)
    atomicAdd(&colacc[2 * lane],           s0);
    atomicAdd(&colacc[2 * lane + 1],       s1);
    atomicAdd(&colacc[128 + 2 * lane],     q0);
    atomicAdd(&colacc[128 + 2 * lane + 1], q1);
    __syncthreads();
    if (threadIdx.x < 256)
        partials[(long)blockIdx.x * 256 + threadIdx.x] = colacc[threadIdx.x];
}

// ---------------- BN stats -> affine a,c (8 blocks x 16 cols) ----------------
__global__ __launch_bounds__(1024) void k_stats(const float* __restrict__ partials,
                                                const float* __restrict__ gamma, const float* __restrict__ beta,
                                                float* __restrict__ ac) {
    __shared__ float ls[1024], lq[1024];
    int dd = threadIdx.x & 15;
    int seg = threadIdx.x >> 4;                    // 64 segments
    int d = blockIdx.x * 16 + dd;
    float s = 0.f, q = 0.f;
    for (int b = seg; b < AGG_BLOCKS; b += 64) {   // 8 iters
        s += partials[b * 256 + d];
        q += partials[b * 256 + 128 + d];
    }
    ls[threadIdx.x] = s; lq[threadIdx.x] = q;
    __syncthreads();
    for (int off = 512; off >= 16; off >>= 1) {
        if (threadIdx.x < off) {
            ls[threadIdx.x] += ls[threadIdx.x + off];
            lq[threadIdx.x] += lq[threadIdx.x + off];
        }
        __syncthreads();
    }
    if (threadIdx.x < 16) {
        s = ls[threadIdx.x]; q = lq[threadIdx.x];
        float mean = s * (1.f / N_NODES);
        float var  = q * (1.f / N_NODES) - mean * mean;
        float a = gamma[d] * rsqrtf(var + BN_EPS);
        ac[d] = a;
        ac[DIM + d] = fmaf(-mean, a, beta[d]);
    }
}

// ---------------- Pool + final MLP fused (per graph) ----------------
__global__ __launch_bounds__(1024) void k_poolmlp(const __half* __restrict__ h, const float* __restrict__ ac,
                                                  const int* __restrict__ goff,
                                                  const float* __restrict__ w1, const float* __restrict__ b1,
                                                  const float* __restrict__ w2, const float* __restrict__ b2,
                                                  float* __restrict__ out) {
    __shared__ float2 red[1024];
    __shared__ float pl[DIM];
    int g = blockIdx.x;
    int d2 = threadIdx.x & 63;                     // col pair
    int seg = threadIdx.x >> 6;                    // 16 segments
    int r0 = goff[g], r1 = goff[g + 1];
    const __half2* rows = (const __half2*)h;
    float s0 = 0.f, s1 = 0.f;
    for (int r = r0 + seg; r < r1; r += 16) {
        float2 v = __half22float2(rows[(long)r * 64 + d2]);
        s0 += v.x; s1 += v.y;
    }
    red[threadIdx.x] = make_float2(s0, s1);
    __syncthreads();
    for (int off = 512; off >= 64; off >>= 1) {
        if (threadIdx.x < off) {
            red[threadIdx.x].x += red[threadIdx.x + off].x;
            red[threadIdx.x].y += red[threadIdx.x + off].y;
        }
        __syncthreads();
    }
    if (threadIdx.x < 64) {
        float2 s = red[threadIdx.x];
        int n = r1 - r0;
        float fn = (float)n;
        float denom = (float)(n > 0 ? n : 1);
        int d = 2 * threadIdx.x;
        pl[d]     = (ac[d] * s.x     + ac[DIM + d] * fn)     / denom;
        pl[d + 1] = (ac[d + 1] * s.y + ac[DIM + d + 1] * fn) / denom;
    }
    __syncthreads();
    if (threadIdx.x < 64) {
        int j = threadIdx.x;
        float hh = b1[j];
#pragma unroll
        for (int k = 0; k < DIM; ++k) hh = fmaf(pl[k], w1[k * 64 + j], hh);
        hh = fmaxf(hh, 0.f);
        float v = hh * w2[j];
#pragma unroll
        for (int o = 32; o > 0; o >>= 1) v += __shfl_down(v, o);
        if (j == 0) out[g] = v + b2[0];
    }
}

extern "C" void kernel_launch(void* const* d_in, const int* in_sizes, int n_in,
                              void* d_out, int out_size, void* d_ws, size_t ws_size,
                              hipStream_t stream) {
    const float* x      = (const float*)d_in[0];
    const int*   ei     = (const int*)d_in[1];
    const int*   batch  = (const int*)d_in[2];
    const float* Ws     = (const float*)d_in[3];
    const float* bs     = (const float*)d_in[4];
    const float* gammas = (const float*)d_in[5];
    const float* betas  = (const float*)d_in[6];
    const float* w1     = (const float*)d_in[7];
    const float* b1     = (const float*)d_in[8];
    const float* w2     = (const float*)d_in[9];
    const float* b2     = (const float*)d_in[10];
    float* out = (float*)d_out;

    char* p = (char*)d_ws;
    auto alloc = [&](size_t bytes) { void* r = (void*)p; p += (bytes + 255) & ~(size_t)255; return r; };
    int*    cnt      = (int*)alloc((size_t)N_NODES * 4);
    int*    off      = (int*)alloc((size_t)(N_NODES + 1) * 4);
    int*    rank     = (int*)alloc((size_t)N_EDGES * 4);
    int*    goff     = (int*)alloc((size_t)(N_GRAPHS + 1) * 4);
    int*    blocksum = (int*)alloc((size_t)(SCAN_NB + 1) * 4);
    int*    elist    = (int*)alloc((size_t)N_EDGES * 4);
    float*  dinv     = (float*)alloc((size_t)N_NODES * 4);
    __half* wt       = (__half*)alloc((size_t)3 * 2 * DIM * WTP * 2);
    __half* h16      = (__half*)alloc((size_t)N_NODES * DIM * 2);
    __half* v16      = (__half*)alloc((size_t)N_NODES * DIM * 2);
    float*  parts    = (float*)alloc((size_t)AGG_BLOCKS * 256 * 4);
    float*  ac       = (float*)alloc(256 * 4);

    hipMemsetAsync(cnt, 0, (size_t)N_NODES * 4, stream);

    k_count_edges<<<(N_EDGES + 255) / 256, 256, 0, stream>>>(ei, cnt, rank);
    k_scan_blk<<<SCAN_NB, 1024, 0, stream>>>(cnt, off, blocksum);
    k_scan_fix<<<SCAN_NB, 1024, 0, stream>>>(cnt, blocksum, off, dinv, batch, goff);
    k_fill_prepw<<<FILL_NB + PREPW_NB, 256, 0, stream>>>(ei, rank, off, elist, Ws, wt);

    for (int l = 0; l < 3; ++l) {
        if (l == 0)
            k_gemm_f32<<<GEMM_BLOCKS, 256, 0, stream>>>(x, wt, bs, h16);
        else
            k_gemm_f16<<<GEMM_BLOCKS, 256, 0, stream>>>(v16, wt + (size_t)l * 2 * DIM * WTP,
                                                        bs + (size_t)l * DIM, ac, h16);
        k_agg<<<AGG_BLOCKS, 1024, 0, stream>>>(h16, off, elist, dinv, v16, parts);
        k_stats<<<8, 1024, 0, stream>>>(parts, gammas + (size_t)l * DIM, betas + (size_t)l * DIM, ac);
    }
    k_poolmlp<<<N_GRAPHS, 1024, 0, stream>>>(v16, ac, goff, w1, b1, w2, b2, out);
}